// Round 4
// baseline (2153.602 us; speedup 1.0000x reference)
//
#include <hip/hip_runtime.h>
#include <math.h>

#define DD 128

typedef __attribute__((ext_vector_type(8))) short short8;   // 8 x bf16 bits
typedef __attribute__((ext_vector_type(4))) float f32x4;

__device__ inline short bf16hi(float x) {
  unsigned u = __float_as_uint(x);
  unsigned r = u + 0x7fffu + ((u >> 16) & 1u);  // RTNE
  return (short)(r >> 16);
}
__device__ inline float bf16tof(short h) {
  return __uint_as_float(((unsigned)(unsigned short)h) << 16);
}
__device__ inline void split2(float x, short& hi, short& lo) {  // RTNE
  hi = bf16hi(x);
  float rem = x - bf16tof(hi);
  lo = bf16hi(rem);
}
__device__ inline void splitT(float x, short& hi, short& lo) {  // truncation (cheap)
  unsigned u = __float_as_uint(x);
  hi = (short)(u >> 16);
  float rem = x - __uint_as_float(u & 0xffff0000u);
  lo = (short)(__float_as_uint(rem) >> 16);
}

// ---------------- small helper kernels ----------------
__global__ __launch_bounds__(128) void zero128_kernel(float* p) { p[threadIdx.x] = 0.f; }

__global__ __launch_bounds__(256) void colsum_kernel(const float* __restrict__ x,
                                                     float* __restrict__ colsum, int N) {
  int col = threadIdx.x & 127;
  int part = (blockIdx.x * blockDim.x + threadIdx.x) >> 7;
  int nparts = (gridDim.x * blockDim.x) >> 7;
  float s = 0.f;
  for (int r = part; r < N; r += nparts) s += x[(size_t)r * DD + col];
  atomicAdd(&colsum[col], s);
}

__global__ __launch_bounds__(128) void glb_kernel(const float* __restrict__ colsum,
                                                  const float* __restrict__ glb_W,
                                                  const float* __restrict__ glb_b,
                                                  float* __restrict__ g, float invN) {
  __shared__ float m[DD];
  int j = threadIdx.x;
  m[j] = colsum[j] * invN;
  __syncthreads();
  float s = glb_b[j];
#pragma unroll 8
  for (int k = 0; k < DD; ++k) s = fmaf(m[k], glb_W[k * DD + j], s);
  g[j] = fmaxf(s, 0.f);
}

// Weight prep.
// WbigF: fragment-major hi/lo for Z-prep GEMM. Wbig[k][col], k in [0,128), col in [0,512):
//   col<128: msg_W1[k][col]; col<256: att_W1[k][col-128];
//   col<384: msg_W1[k+128][col-256]; else att_W1[k+128][col-384].
//   Frag slot (c in [0,4) kchunk, n in [0,32) ntile, p plane, lane): elem j:
//   col=n*16+(lane&15), k=c*32+(lane>>4)*8+j. Linear i=((c*32+n)*2+p)*64+lane.
// W2F: same frag-major for msg_W2 (4 chunks x 8 ntiles).
// U1T/U2T: col-major hi/lo planes for the node kernel.
__global__ __launch_bounds__(256) void conv_kernel(
    const float* __restrict__ msg_W1, const float* __restrict__ att_W1,
    const float* __restrict__ msg_W2, const float* __restrict__ upd_W1,
    const float* __restrict__ upd_W2,
    short* __restrict__ WbigF, short* __restrict__ W2F,
    short* __restrict__ U1hiT, short* __restrict__ U1loT,
    short* __restrict__ U2hiT, short* __restrict__ U2loT) {
  int i = blockIdx.x * 256 + threadIdx.x;  // 0 .. 69631
  if (i < 16384) {
    int lane = i & 63, p = (i >> 6) & 1, n = (i >> 7) & 31, c = i >> 12;
    int col = n * 16 + (lane & 15);
#pragma unroll
    for (int j = 0; j < 8; ++j) {
      int k = c * 32 + ((lane >> 4) & 3) * 8 + j;
      float v;
      if (col < 128)      v = msg_W1[k * 128 + col];
      else if (col < 256) v = att_W1[k * 128 + (col - 128)];
      else if (col < 384) v = msg_W1[(k + 128) * 128 + (col - 256)];
      else                v = att_W1[(k + 128) * 128 + (col - 384)];
      short hi, lo; splitT(v, hi, lo);
      WbigF[(size_t)i * 8 + j] = p ? lo : hi;
    }
  } else if (i < 20480) {
    int gI = i - 16384;
    int lane = gI & 63, p = (gI >> 6) & 1, n = (gI >> 7) & 7, c = gI >> 10;
    int col = n * 16 + (lane & 15);
#pragma unroll
    for (int j = 0; j < 8; ++j) {
      int k = c * 32 + ((lane >> 4) & 3) * 8 + j;
      float v = msg_W2[k * 128 + col];
      short hi, lo; splitT(v, hi, lo);
      W2F[(size_t)gI * 8 + j] = p ? lo : hi;
    }
  } else if (i < 53248) {
    int j = i - 20480;  // col 0..127, k 0..255
    int col = j & 127, k = j >> 7;
    float v = upd_W1[k * 128 + col];
    short hi, lo; split2(v, hi, lo);
    U1hiT[col * 256 + k] = hi; U1loT[col * 256 + k] = lo;
  } else if (i < 69632) {
    int j = i - 53248;
    int col = j & 127, k = (j >> 7) & 127;
    float v = upd_W2[k * 128 + col];
    short hi, lo; split2(v, hi, lo);
    U2hiT[col * 128 + k] = hi; U2loT[col * 128 + k] = lo;
  }
}

// ---------------- Z-prep GEMM: Z[N x 512] = h @ Wbig (+ [msg_b1|att_b1|0|0]) ----
// Block: 256 thr = 4 waves; 32 rows x 512 cols; wave w -> cols [w*128, w*128+128).
template <int ZF>
__global__ __launch_bounds__(256, 2) void zprep_kernel(
    const float* __restrict__ h, const short* __restrict__ WbigF,
    const float* __restrict__ msg_b1, const float* __restrict__ att_b1,
    void* __restrict__ Zv, int N) {
  const int tid = threadIdx.x;
  const int w = tid >> 6;
  const int lane = tid & 63;
  const int m16 = lane & 15, q = lane >> 4;
  const int r0 = blockIdx.x * 32;

  f32x4 acc[2][8];
#pragma unroll
  for (int nt = 0; nt < 8; ++nt) {
    int col = w * 128 + nt * 16 + m16;
    float b = (col < 128) ? msg_b1[col] : ((col < 256) ? att_b1[col - 128] : 0.f);
    acc[0][nt] = (f32x4){b, b, b, b};
    acc[1][nt] = (f32x4){b, b, b, b};
  }

  for (int c = 0; c < 4; ++c) {
    short8 ah[2], al[2];
#pragma unroll
    for (int mt = 0; mt < 2; ++mt) {
      int row = min(r0 + mt * 16 + m16, N - 1);
      const float* p = h + (size_t)row * DD + c * 32 + q * 8;
      float4 v0 = *(const float4*)p;
      float4 v1 = *(const float4*)(p + 4);
      float f[8] = {v0.x, v0.y, v0.z, v0.w, v1.x, v1.y, v1.z, v1.w};
#pragma unroll
      for (int j = 0; j < 8; ++j) { short hi, lo; splitT(f[j], hi, lo); ah[mt][j] = hi; al[mt][j] = lo; }
    }
#pragma unroll
    for (int nt = 0; nt < 8; ++nt) {
      int ng = w * 8 + nt;
      const short* bp = WbigF + ((size_t)((c * 32 + ng) * 2) * 64 + lane) * 8;
      short8 bh = *(const short8*)bp;
      short8 bl = *(const short8*)(bp + 512);
#pragma unroll
      for (int mt = 0; mt < 2; ++mt) {
        acc[mt][nt] = __builtin_amdgcn_mfma_f32_16x16x32_bf16(ah[mt], bh, acc[mt][nt], 0, 0, 0);
        acc[mt][nt] = __builtin_amdgcn_mfma_f32_16x16x32_bf16(al[mt], bh, acc[mt][nt], 0, 0, 0);
        acc[mt][nt] = __builtin_amdgcn_mfma_f32_16x16x32_bf16(ah[mt], bl, acc[mt][nt], 0, 0, 0);
      }
    }
  }

#pragma unroll
  for (int mt = 0; mt < 2; ++mt)
#pragma unroll
    for (int r = 0; r < 4; ++r) {
      int row = r0 + mt * 16 + q * 4 + r;
      if (row < N) {
#pragma unroll
        for (int nt = 0; nt < 8; ++nt) {
          int col = w * 128 + nt * 16 + m16;
          if (ZF == 0)
            ((float*)Zv)[(size_t)row * 512 + col] = acc[mt][nt][r];
          else
            ((unsigned short*)Zv)[(size_t)row * 512 + col] =
                (unsigned short)bf16hi(acc[mt][nt][r]);
        }
      }
    }
}

// ---------------- edge kernel: pure gather/add/relu/dot/scatter ----------------
// 32 lanes per edge; lane c owns cols 4c..4c+3.
// hid = relu(Z[s][0:128] + Z[d][256:384]); ahid = relu(Z[s][128:256] + Z[d][384:512]).
// att = sigmoid(dot(ahid, att_W2) + b2); aggH[d] += att*hid; aggA[d] += att.
template <int ZF>
__global__ __launch_bounds__(256) void edge_kernel(
    const void* __restrict__ Zv, const int* __restrict__ src, const int* __restrict__ dst,
    const float* __restrict__ att_W2, const float* __restrict__ att_b2,
    float* __restrict__ aggH, float* __restrict__ aggA, int E) {
  int t = blockIdx.x * 256 + threadIdx.x;
  int e = t >> 5;
  int c = t & 31;
  if (e >= E) return;
  int s = src[e], d = dst[e];

  float hm[4], ha[4];
  if (ZF == 0) {
    const float4* Sp = (const float4*)((const float*)Zv + (size_t)s * 512);
    const float4* Dp = (const float4*)((const float*)Zv + (size_t)d * 512 + 256);
    float4 sm = Sp[c], dm = Dp[c];
    float4 sa = Sp[32 + c], da = Dp[32 + c];
    hm[0] = sm.x + dm.x; hm[1] = sm.y + dm.y; hm[2] = sm.z + dm.z; hm[3] = sm.w + dm.w;
    ha[0] = sa.x + da.x; ha[1] = sa.y + da.y; ha[2] = sa.z + da.z; ha[3] = sa.w + da.w;
  } else {
    const unsigned short* Sp = (const unsigned short*)Zv + (size_t)s * 512;
    const unsigned short* Dp = (const unsigned short*)Zv + (size_t)d * 512 + 256;
    uint2 usm = *(const uint2*)(Sp + 4 * c), udm = *(const uint2*)(Dp + 4 * c);
    uint2 usa = *(const uint2*)(Sp + 128 + 4 * c), uda = *(const uint2*)(Dp + 128 + 4 * c);
    hm[0] = bf16tof((short)(usm.x & 0xffff)) + bf16tof((short)(udm.x & 0xffff));
    hm[1] = bf16tof((short)(usm.x >> 16))   + bf16tof((short)(udm.x >> 16));
    hm[2] = bf16tof((short)(usm.y & 0xffff)) + bf16tof((short)(udm.y & 0xffff));
    hm[3] = bf16tof((short)(usm.y >> 16))   + bf16tof((short)(udm.y >> 16));
    ha[0] = bf16tof((short)(usa.x & 0xffff)) + bf16tof((short)(uda.x & 0xffff));
    ha[1] = bf16tof((short)(usa.x >> 16))   + bf16tof((short)(uda.x >> 16));
    ha[2] = bf16tof((short)(usa.y & 0xffff)) + bf16tof((short)(uda.y & 0xffff));
    ha[3] = bf16tof((short)(usa.y >> 16))   + bf16tof((short)(uda.y >> 16));
  }
#pragma unroll
  for (int i = 0; i < 4; ++i) {
    hm[i] = fmaxf(hm[i], 0.f);
    ha[i] = fmaxf(ha[i], 0.f);
  }
  float4 aw = *(const float4*)(att_W2 + 4 * c);
  float p = fmaf(ha[0], aw.x, fmaf(ha[1], aw.y, fmaf(ha[2], aw.z, ha[3] * aw.w)));
#pragma unroll
  for (int off = 1; off < 32; off <<= 1) p += __shfl_xor(p, off);
  float att = 1.f / (1.f + expf(-(p + att_b2[0])));

  float* base = aggH + (size_t)d * DD + 4 * c;
#pragma unroll
  for (int i = 0; i < 4; ++i) atomicAdd(base + i, hm[i] * att);
  if (c == 0) atomicAdd(aggA + d, att);
}

// ---------------- agg GEMM (in-place): aggH = aggH @ W2 + aggA (x) msg_b2 ----------------
// Block: 256 thr = 4 waves; wave w -> rows [blk*64 + w*16, +16), all 128 cols.
__global__ __launch_bounds__(256, 4) void agggemm_kernel(
    float* __restrict__ aggH, const float* __restrict__ aggA,
    const short* __restrict__ W2F, const float* __restrict__ msg_b2, int N) {
  const int tid = threadIdx.x;
  const int w = tid >> 6;
  const int lane = tid & 63;
  const int m16 = lane & 15, q = lane >> 4;
  const int r0 = blockIdx.x * 64 + w * 16;

  f32x4 acc[8];
#pragma unroll
  for (int nt = 0; nt < 8; ++nt) acc[nt] = (f32x4){0.f, 0.f, 0.f, 0.f};

  for (int c2 = 0; c2 < 4; ++c2) {
    int row = min(r0 + m16, N - 1);
    const float* p = aggH + (size_t)row * DD + c2 * 32 + q * 8;
    float4 v0 = *(const float4*)p;
    float4 v1 = *(const float4*)(p + 4);
    float f[8] = {v0.x, v0.y, v0.z, v0.w, v1.x, v1.y, v1.z, v1.w};
    short8 ah, al;
#pragma unroll
    for (int j = 0; j < 8; ++j) { short hi, lo; splitT(f[j], hi, lo); ah[j] = hi; al[j] = lo; }
#pragma unroll
    for (int nt = 0; nt < 8; ++nt) {
      const short* bp = W2F + ((size_t)((c2 * 8 + nt) * 2) * 64 + lane) * 8;
      short8 bh = *(const short8*)bp;
      short8 bl = *(const short8*)(bp + 512);
      acc[nt] = __builtin_amdgcn_mfma_f32_16x16x32_bf16(ah, bh, acc[nt], 0, 0, 0);
      acc[nt] = __builtin_amdgcn_mfma_f32_16x16x32_bf16(al, bh, acc[nt], 0, 0, 0);
      acc[nt] = __builtin_amdgcn_mfma_f32_16x16x32_bf16(ah, bl, acc[nt], 0, 0, 0);
    }
  }

#pragma unroll
  for (int r = 0; r < 4; ++r) {
    int row = r0 + q * 4 + r;
    if (row < N) {
      float av = aggA[row];
#pragma unroll
      for (int nt = 0; nt < 8; ++nt) {
        int col = nt * 16 + m16;
        aggH[(size_t)row * DD + col] = acc[nt][r] + av * msg_b2[col];
      }
    }
  }
}

// ---------------- node update kernel (unchanged, verified) ----------------
__global__ __launch_bounds__(256, 2) void node_mfma_kernel(
    const float* __restrict__ h, const float* __restrict__ agg,
    const short* __restrict__ U1hiT, const short* __restrict__ U1loT,
    const short* __restrict__ U2hiT, const short* __restrict__ U2loT,
    const float* __restrict__ upd_b1, const float* __restrict__ upd_b2,
    const float* __restrict__ g, float* __restrict__ out, int N) {
  __shared__ short smem[29184];
  short* WT1hi = smem;            // 128 cols x 40
  short* WT1lo = smem + 5120;
  short* HIDlo = smem + 10240;
  short* HIDhi = smem + 20480;

  const int tid = threadIdx.x;
  const int wave = tid >> 6;
  const int lane = tid & 63;
  const int m16 = lane & 15;
  const int q = lane >> 4;

  const int n0 = blockIdx.x * 64;
  const int nA = n0 + wave * 16 + m16;
  const int nAc = min(nA, N - 1);

  short8 a1h[8], a1l[8];
  {
    const float* rs = h + (size_t)nAc * DD;
    const float* rd = agg + (size_t)nAc * DD;
#pragma unroll
    for (int t = 0; t < 8; ++t) {
      const float* base = ((t < 4) ? (rs + t * 32) : (rd + (t - 4) * 32)) + q * 8;
      float4 v0 = *(const float4*)(base);
      float4 v1 = *(const float4*)(base + 4);
      float f[8] = {v0.x, v0.y, v0.z, v0.w, v1.x, v1.y, v1.z, v1.w};
      short8 hh, ll;
#pragma unroll
      for (int j = 0; j < 8; ++j) { short hi, lo; split2(f[j], hi, lo); hh[j] = hi; ll[j] = lo; }
      a1h[t] = hh; a1l[t] = ll;
    }
  }

  f32x4 acc[8];
#pragma unroll
  for (int n = 0; n < 8; ++n) {
    float b = upd_b1[n * 16 + m16];
    acc[n] = (f32x4){b, b, b, b};
  }

  for (int t = 0; t < 8; ++t) {
    __syncthreads();
#pragma unroll
    for (int r = 0; r < 4; ++r) {
      int idx = tid + 256 * r;
      int comp = idx >> 9;
      int cid = idx & 511;
      int col = cid >> 2, sub = cid & 3;
      const short* gsrc = (comp ? U1loT : U1hiT) + col * 256 + t * 32 + sub * 8;
      short* ldst = (comp ? WT1lo : WT1hi) + col * 40 + sub * 8;
      *(short8*)ldst = *(const short8*)gsrc;
    }
    __syncthreads();
#pragma unroll
    for (int n = 0; n < 8; ++n) {
      const short* bp = WT1hi + (n * 16 + m16) * 40 + q * 8;
      short8 bh = *(const short8*)bp;
      short8 bl = *(const short8*)(bp + 5120);
      acc[n] = __builtin_amdgcn_mfma_f32_16x16x32_bf16(a1h[t], bh, acc[n], 0, 0, 0);
      acc[n] = __builtin_amdgcn_mfma_f32_16x16x32_bf16(a1l[t], bh, acc[n], 0, 0, 0);
      acc[n] = __builtin_amdgcn_mfma_f32_16x16x32_bf16(a1h[t], bl, acc[n], 0, 0, 0);
    }
  }

  __syncthreads();
#pragma unroll
  for (int n = 0; n < 8; ++n) {
    int col = n * 16 + m16;
#pragma unroll
    for (int r = 0; r < 4; ++r) {
      int row = wave * 16 + q * 4 + r;
      float v = fmaxf(acc[n][r], 0.f);
      short hi, lo; split2(v, hi, lo);
      HIDhi[row * 136 + col] = hi;
      HIDlo[row * 136 + col] = lo;
    }
  }
  __syncthreads();

  short8 a2h[4], a2l[4];
  {
    int mrow = wave * 16 + m16;
#pragma unroll
    for (int t = 0; t < 4; ++t) {
      a2h[t] = *(const short8*)(HIDhi + mrow * 136 + t * 32 + q * 8);
      a2l[t] = *(const short8*)(HIDlo + mrow * 136 + t * 32 + q * 8);
    }
  }

  f32x4 acc2[8];
#pragma unroll
  for (int n = 0; n < 8; ++n) {
    float b = upd_b2[n * 16 + m16];
    acc2[n] = (f32x4){b, b, b, b};
  }

  for (int t = 0; t < 4; ++t) {
    __syncthreads();
#pragma unroll
    for (int r = 0; r < 4; ++r) {
      int idx = tid + 256 * r;
      int comp = idx >> 9;
      int cid = idx & 511;
      int col = cid >> 2, sub = cid & 3;
      const short* gsrc = (comp ? U2loT : U2hiT) + col * 128 + t * 32 + sub * 8;
      short* ldst = (comp ? WT1lo : WT1hi) + col * 40 + sub * 8;
      *(short8*)ldst = *(const short8*)gsrc;
    }
    __syncthreads();
#pragma unroll
    for (int n = 0; n < 8; ++n) {
      const short* bp = WT1hi + (n * 16 + m16) * 40 + q * 8;
      short8 bh = *(const short8*)bp;
      short8 bl = *(const short8*)(bp + 5120);
      acc2[n] = __builtin_amdgcn_mfma_f32_16x16x32_bf16(a2h[t], bh, acc2[n], 0, 0, 0);
      acc2[n] = __builtin_amdgcn_mfma_f32_16x16x32_bf16(a2l[t], bh, acc2[n], 0, 0, 0);
      acc2[n] = __builtin_amdgcn_mfma_f32_16x16x32_bf16(a2h[t], bl, acc2[n], 0, 0, 0);
    }
  }

#pragma unroll
  for (int r = 0; r < 4; ++r) {
    int rowN = n0 + wave * 16 + q * 4 + r;
    if (rowN < N) {
#pragma unroll
      for (int n = 0; n < 8; ++n) {
        int col = n * 16 + m16;
        out[(size_t)rowN * DD + col] = acc2[n][r] + h[(size_t)rowN * DD + col] + g[col];
      }
    }
  }
}

extern "C" void kernel_launch(void* const* d_in, const int* in_sizes, int n_in,
                              void* d_out, int out_size, void* d_ws, size_t ws_size,
                              hipStream_t stream) {
  const float* x = (const float*)d_in[0];
  const int* ei = (const int*)d_in[1];
  const float* msg_W1 = (const float*)d_in[2];
  const float* msg_b1 = (const float*)d_in[3];
  const float* msg_W2 = (const float*)d_in[4];
  const float* msg_b2 = (const float*)d_in[5];
  const float* upd_W1 = (const float*)d_in[6];
  const float* upd_b1 = (const float*)d_in[7];
  const float* upd_W2 = (const float*)d_in[8];
  const float* upd_b2 = (const float*)d_in[9];
  const float* att_W1 = (const float*)d_in[10];
  const float* att_b1 = (const float*)d_in[11];
  const float* att_W2 = (const float*)d_in[12];
  const float* att_b2 = (const float*)d_in[13];
  const float* glb_W = (const float*)d_in[14];
  const float* glb_b = (const float*)d_in[15];

  const int N = in_sizes[0] / DD;
  const int E = in_sizes[1] / 2;
  const int* src = ei;
  const int* dst = ei + E;

  float* out = (float*)d_out;
  float* aggH = (float*)d_ws;                  // N*128
  float* aggA = aggH + (size_t)N * DD;         // N (contiguous after aggH for one memset)
  float* colsum = aggA + N;                    // 128
  float* g = colsum + DD;                      // 128
  short* WbigF = (short*)(g + DD);             // 131072 shorts
  short* W2F = WbigF + 131072;                 // 32768
  short* U1hiT = W2F + 32768;                  // 32768
  short* U1loT = U1hiT + 32768;                // 32768
  short* U2hiT = U1loT + 32768;                // 16384
  short* U2loT = U2hiT + 16384;                // 16384
  void* Z = (void*)(U2loT + 16384);            // N*512 (f32 or bf16)

  size_t fixed_bytes = (size_t)((char*)Z - (char*)d_ws);
  size_t need32 = fixed_bytes + (size_t)N * 512 * 4;
  const bool z16 = (ws_size < need32);  // fallback: bf16 Z (half the footprint)

  conv_kernel<<<272, 256, 0, stream>>>(msg_W1, att_W1, msg_W2, upd_W1, upd_W2,
                                       WbigF, W2F, U1hiT, U1loT, U2hiT, U2loT);
  zero128_kernel<<<1, 128, 0, stream>>>(colsum);
  colsum_kernel<<<256, 256, 0, stream>>>(x, colsum, N);
  glb_kernel<<<1, 128, 0, stream>>>(colsum, glb_W, glb_b, g, 1.0f / (float)N);

  const int zgrid = (N + 31) / 32;
  const int egrid = (int)(((size_t)E * 32 + 255) / 256);
  const int ngrid = (N + 63) / 64;
  for (int step = 0; step < 2; ++step) {
    const float* hptr = (step == 0) ? x : out;
    hipMemsetAsync(aggH, 0, (size_t)(N * DD + N) * sizeof(float), stream);
    if (!z16) {
      zprep_kernel<0><<<zgrid, 256, 0, stream>>>(hptr, WbigF, msg_b1, att_b1, Z, N);
      edge_kernel<0><<<egrid, 256, 0, stream>>>(Z, src, dst, att_W2, att_b2, aggH, aggA, E);
    } else {
      zprep_kernel<1><<<zgrid, 256, 0, stream>>>(hptr, WbigF, msg_b1, att_b1, Z, N);
      edge_kernel<1><<<egrid, 256, 0, stream>>>(Z, src, dst, att_W2, att_b2, aggH, aggA, E);
    }
    agggemm_kernel<<<ngrid, 256, 0, stream>>>(aggH, aggA, W2F, msg_b2, N);
    node_mfma_kernel<<<ngrid, 256, 0, stream>>>(hptr, aggH, U1hiT, U1loT, U2hiT, U2loT,
                                                upd_b1, upd_b2, g, out, N);
  }
}

// Round 5
// 696.202 us; speedup vs baseline: 3.0934x; 3.0934x over previous
//
#include <hip/hip_runtime.h>
#include <math.h>

#define DD 128

typedef __attribute__((ext_vector_type(8))) short short8;   // 8 x bf16 bits
typedef __attribute__((ext_vector_type(4))) float f32x4;

__device__ inline short bf16hi(float x) {
  unsigned u = __float_as_uint(x);
  unsigned r = u + 0x7fffu + ((u >> 16) & 1u);  // RTNE
  return (short)(r >> 16);
}
__device__ inline float bf16tof(short h) {
  return __uint_as_float(((unsigned)(unsigned short)h) << 16);
}
__device__ inline void split2(float x, short& hi, short& lo) {  // RTNE
  hi = bf16hi(x);
  float rem = x - bf16tof(hi);
  lo = bf16hi(rem);
}
__device__ inline void splitT(float x, short& hi, short& lo) {  // truncation (cheap)
  unsigned u = __float_as_uint(x);
  hi = (short)(u >> 16);
  float rem = x - __uint_as_float(u & 0xffff0000u);
  lo = (short)(__float_as_uint(rem) >> 16);
}

// ---------------- small helper kernels ----------------
__global__ __launch_bounds__(128) void zero128_kernel(float* p) { p[threadIdx.x] = 0.f; }

__global__ __launch_bounds__(256) void colsum_kernel(const float* __restrict__ x,
                                                     float* __restrict__ colsum, int N) {
  int col = threadIdx.x & 127;
  int part = (blockIdx.x * blockDim.x + threadIdx.x) >> 7;
  int nparts = (gridDim.x * blockDim.x) >> 7;
  float s = 0.f;
  for (int r = part; r < N; r += nparts) s += x[(size_t)r * DD + col];
  atomicAdd(&colsum[col], s);
}

__global__ __launch_bounds__(128) void glb_kernel(const float* __restrict__ colsum,
                                                  const float* __restrict__ glb_W,
                                                  const float* __restrict__ glb_b,
                                                  float* __restrict__ g, float invN) {
  __shared__ float m[DD];
  int j = threadIdx.x;
  m[j] = colsum[j] * invN;
  __syncthreads();
  float s = glb_b[j];
#pragma unroll 8
  for (int k = 0; k < DD; ++k) s = fmaf(m[k], glb_W[k * DD + j], s);
  g[j] = fmaxf(s, 0.f);
}

// ---------------- CSR build: histogram -> scan -> scatter ----------------
__global__ __launch_bounds__(256) void hist_kernel(const int* __restrict__ dst,
                                                   int* __restrict__ rowptr, int E) {
  for (int e = blockIdx.x * blockDim.x + threadIdx.x; e < E; e += gridDim.x * blockDim.x)
    atomicAdd(&rowptr[dst[e] + 1], 1);
}

// single-block chunked inclusive scan over a[0..n)
__global__ __launch_bounds__(1024) void scan_kernel(int* __restrict__ a, int n) {
  __shared__ int buf[1024];
  __shared__ int carry;
  const int tid = threadIdx.x;
  if (tid == 0) carry = 0;
  __syncthreads();
  for (int base = 0; base < n; base += 1024) {
    int i = base + tid;
    int v = (i < n) ? a[i] : 0;
    buf[tid] = v;
    __syncthreads();
#pragma unroll
    for (int off = 1; off < 1024; off <<= 1) {
      int t = (tid >= off) ? buf[tid - off] : 0;
      __syncthreads();
      buf[tid] += t;
      __syncthreads();
    }
    if (i < n) a[i] = buf[tid] + carry;
    int last = buf[1023];
    __syncthreads();
    if (tid == 0) carry += last;
    __syncthreads();
  }
}

__global__ __launch_bounds__(256) void scatter_kernel(const int* __restrict__ src,
                                                      const int* __restrict__ dst,
                                                      int* __restrict__ cursor,
                                                      int* __restrict__ sortedSrc, int E) {
  for (int e = blockIdx.x * blockDim.x + threadIdx.x; e < E; e += gridDim.x * blockDim.x) {
    int pos = atomicAdd(&cursor[dst[e]], 1);
    sortedSrc[pos] = src[e];
  }
}

// ---------------- weight prep (frag-major hi/lo + col-major planes) ----------------
__global__ __launch_bounds__(256) void conv_kernel(
    const float* __restrict__ msg_W1, const float* __restrict__ att_W1,
    const float* __restrict__ msg_W2, const float* __restrict__ upd_W1,
    const float* __restrict__ upd_W2,
    short* __restrict__ WbigF, short* __restrict__ W2F,
    short* __restrict__ U1hiT, short* __restrict__ U1loT,
    short* __restrict__ U2hiT, short* __restrict__ U2loT) {
  int i = blockIdx.x * 256 + threadIdx.x;  // 0 .. 69631
  if (i < 16384) {
    int lane = i & 63, p = (i >> 6) & 1, n = (i >> 7) & 31, c = i >> 12;
    int col = n * 16 + (lane & 15);
#pragma unroll
    for (int j = 0; j < 8; ++j) {
      int k = c * 32 + ((lane >> 4) & 3) * 8 + j;
      float v;
      if (col < 128)      v = msg_W1[k * 128 + col];
      else if (col < 256) v = att_W1[k * 128 + (col - 128)];
      else if (col < 384) v = msg_W1[(k + 128) * 128 + (col - 256)];
      else                v = att_W1[(k + 128) * 128 + (col - 384)];
      short hi, lo; splitT(v, hi, lo);
      WbigF[(size_t)i * 8 + j] = p ? lo : hi;
    }
  } else if (i < 20480) {
    int gI = i - 16384;
    int lane = gI & 63, p = (gI >> 6) & 1, n = (gI >> 7) & 7, c = gI >> 10;
    int col = n * 16 + (lane & 15);
#pragma unroll
    for (int j = 0; j < 8; ++j) {
      int k = c * 32 + ((lane >> 4) & 3) * 8 + j;
      float v = msg_W2[k * 128 + col];
      short hi, lo; splitT(v, hi, lo);
      W2F[(size_t)gI * 8 + j] = p ? lo : hi;
    }
  } else if (i < 53248) {
    int j = i - 20480;  // col 0..127, k 0..255
    int col = j & 127, k = j >> 7;
    float v = upd_W1[k * 128 + col];
    short hi, lo; split2(v, hi, lo);
    U1hiT[col * 256 + k] = hi; U1loT[col * 256 + k] = lo;
  } else if (i < 69632) {
    int j = i - 53248;
    int col = j & 127, k = (j >> 7) & 127;
    float v = upd_W2[k * 128 + col];
    short hi, lo; split2(v, hi, lo);
    U2hiT[col * 128 + k] = hi; U2loT[col * 128 + k] = lo;
  }
}

// ---------------- Z-prep GEMM: Z[N x 512] = h @ Wbig (+ [msg_b1|att_b1|0|0]) ----
__global__ __launch_bounds__(256, 2) void zprep_kernel(
    const float* __restrict__ h, const short* __restrict__ WbigF,
    const float* __restrict__ msg_b1, const float* __restrict__ att_b1,
    float* __restrict__ Z, int N) {
  const int tid = threadIdx.x;
  const int w = tid >> 6;
  const int lane = tid & 63;
  const int m16 = lane & 15, q = lane >> 4;
  const int r0 = blockIdx.x * 32;

  f32x4 acc[2][8];
#pragma unroll
  for (int nt = 0; nt < 8; ++nt) {
    int col = w * 128 + nt * 16 + m16;
    float b = (col < 128) ? msg_b1[col] : ((col < 256) ? att_b1[col - 128] : 0.f);
    acc[0][nt] = (f32x4){b, b, b, b};
    acc[1][nt] = (f32x4){b, b, b, b};
  }

  for (int c = 0; c < 4; ++c) {
    short8 ah[2], al[2];
#pragma unroll
    for (int mt = 0; mt < 2; ++mt) {
      int row = min(r0 + mt * 16 + m16, N - 1);
      const float* p = h + (size_t)row * DD + c * 32 + q * 8;
      float4 v0 = *(const float4*)p;
      float4 v1 = *(const float4*)(p + 4);
      float f[8] = {v0.x, v0.y, v0.z, v0.w, v1.x, v1.y, v1.z, v1.w};
#pragma unroll
      for (int j = 0; j < 8; ++j) { short hi, lo; splitT(f[j], hi, lo); ah[mt][j] = hi; al[mt][j] = lo; }
    }
#pragma unroll
    for (int nt = 0; nt < 8; ++nt) {
      int ng = w * 8 + nt;
      const short* bp = WbigF + ((size_t)((c * 32 + ng) * 2) * 64 + lane) * 8;
      short8 bh = *(const short8*)bp;
      short8 bl = *(const short8*)(bp + 512);
#pragma unroll
      for (int mt = 0; mt < 2; ++mt) {
        acc[mt][nt] = __builtin_amdgcn_mfma_f32_16x16x32_bf16(ah[mt], bh, acc[mt][nt], 0, 0, 0);
        acc[mt][nt] = __builtin_amdgcn_mfma_f32_16x16x32_bf16(al[mt], bh, acc[mt][nt], 0, 0, 0);
        acc[mt][nt] = __builtin_amdgcn_mfma_f32_16x16x32_bf16(ah[mt], bl, acc[mt][nt], 0, 0, 0);
      }
    }
  }

#pragma unroll
  for (int mt = 0; mt < 2; ++mt)
#pragma unroll
    for (int r = 0; r < 4; ++r) {
      int row = r0 + mt * 16 + q * 4 + r;
      if (row < N) {
#pragma unroll
        for (int nt = 0; nt < 8; ++nt) {
          int col = w * 128 + nt * 16 + m16;
          Z[(size_t)row * 512 + col] = acc[mt][nt][r];
        }
      }
    }
}

// ---------------- CSR aggregation: no atomics ----------------
// 32 lanes per node; lane c owns cols 4c..4c+3 of both msg and att halves.
// hid = relu(Z[s][0:128] + Z[n][256:384]); ahid = relu(Z[s][128:256] + Z[n][384:512]).
// att = sigmoid(dot(ahid, att_W2) + b2); aggH[n] = sum att*hid; aggA[n] = sum att.
__global__ __launch_bounds__(256) void aggcsr_kernel(
    const float* __restrict__ Z, const int* __restrict__ rowptr,
    const int* __restrict__ sortedSrc, const float* __restrict__ att_W2,
    const float* __restrict__ att_b2, float* __restrict__ aggH,
    float* __restrict__ aggA, int N) {
  const int node = blockIdx.x * 8 + (threadIdx.x >> 5);
  const int c = threadIdx.x & 31;
  if (node >= N) return;

  const float4 aw = *(const float4*)(att_W2 + 4 * c);
  const float ab2 = att_b2[0];
  const float* Zn = Z + (size_t)node * 512;
  const float4 dm = *(const float4*)(Zn + 256 + 4 * c);
  const float4 da = *(const float4*)(Zn + 384 + 4 * c);

  float aH0 = 0.f, aH1 = 0.f, aH2 = 0.f, aH3 = 0.f, aA = 0.f;
  const int b = rowptr[node], e = rowptr[node + 1];

  int i = b;
  for (; i + 1 < e; i += 2) {
    int s0 = sortedSrc[i], s1 = sortedSrc[i + 1];
    const float* Z0 = Z + (size_t)s0 * 512 + 4 * c;
    const float* Z1 = Z + (size_t)s1 * 512 + 4 * c;
    float4 sm0 = *(const float4*)Z0;
    float4 sa0 = *(const float4*)(Z0 + 128);
    float4 sm1 = *(const float4*)Z1;
    float4 sa1 = *(const float4*)(Z1 + 128);

    float h00 = fmaxf(sm0.x + dm.x, 0.f), h01 = fmaxf(sm0.y + dm.y, 0.f);
    float h02 = fmaxf(sm0.z + dm.z, 0.f), h03 = fmaxf(sm0.w + dm.w, 0.f);
    float a00 = fmaxf(sa0.x + da.x, 0.f), a01 = fmaxf(sa0.y + da.y, 0.f);
    float a02 = fmaxf(sa0.z + da.z, 0.f), a03 = fmaxf(sa0.w + da.w, 0.f);
    float h10 = fmaxf(sm1.x + dm.x, 0.f), h11 = fmaxf(sm1.y + dm.y, 0.f);
    float h12 = fmaxf(sm1.z + dm.z, 0.f), h13 = fmaxf(sm1.w + dm.w, 0.f);
    float a10 = fmaxf(sa1.x + da.x, 0.f), a11 = fmaxf(sa1.y + da.y, 0.f);
    float a12 = fmaxf(sa1.z + da.z, 0.f), a13 = fmaxf(sa1.w + da.w, 0.f);

    float p0 = fmaf(a00, aw.x, fmaf(a01, aw.y, fmaf(a02, aw.z, a03 * aw.w)));
    float p1 = fmaf(a10, aw.x, fmaf(a11, aw.y, fmaf(a12, aw.z, a13 * aw.w)));
#pragma unroll
    for (int off = 1; off < 32; off <<= 1) {
      p0 += __shfl_xor(p0, off);
      p1 += __shfl_xor(p1, off);
    }
    float t0 = 1.f / (1.f + expf(-(p0 + ab2)));
    float t1 = 1.f / (1.f + expf(-(p1 + ab2)));
    aA += t0 + t1;
    aH0 = fmaf(t0, h00, fmaf(t1, h10, aH0));
    aH1 = fmaf(t0, h01, fmaf(t1, h11, aH1));
    aH2 = fmaf(t0, h02, fmaf(t1, h12, aH2));
    aH3 = fmaf(t0, h03, fmaf(t1, h13, aH3));
  }
  if (i < e) {
    int s0 = sortedSrc[i];
    const float* Z0 = Z + (size_t)s0 * 512 + 4 * c;
    float4 sm0 = *(const float4*)Z0;
    float4 sa0 = *(const float4*)(Z0 + 128);
    float h00 = fmaxf(sm0.x + dm.x, 0.f), h01 = fmaxf(sm0.y + dm.y, 0.f);
    float h02 = fmaxf(sm0.z + dm.z, 0.f), h03 = fmaxf(sm0.w + dm.w, 0.f);
    float a00 = fmaxf(sa0.x + da.x, 0.f), a01 = fmaxf(sa0.y + da.y, 0.f);
    float a02 = fmaxf(sa0.z + da.z, 0.f), a03 = fmaxf(sa0.w + da.w, 0.f);
    float p0 = fmaf(a00, aw.x, fmaf(a01, aw.y, fmaf(a02, aw.z, a03 * aw.w)));
#pragma unroll
    for (int off = 1; off < 32; off <<= 1) p0 += __shfl_xor(p0, off);
    float t0 = 1.f / (1.f + expf(-(p0 + ab2)));
    aA += t0;
    aH0 = fmaf(t0, h00, aH0);
    aH1 = fmaf(t0, h01, aH1);
    aH2 = fmaf(t0, h02, aH2);
    aH3 = fmaf(t0, h03, aH3);
  }

  *(float4*)(aggH + (size_t)node * DD + 4 * c) = (float4){aH0, aH1, aH2, aH3};
  if (c == 0) aggA[node] = aA;
}

// ---------------- agg GEMM (in-place): aggH = aggH @ W2 + aggA (x) msg_b2 ----------------
__global__ __launch_bounds__(256, 4) void agggemm_kernel(
    float* __restrict__ aggH, const float* __restrict__ aggA,
    const short* __restrict__ W2F, const float* __restrict__ msg_b2, int N) {
  const int tid = threadIdx.x;
  const int w = tid >> 6;
  const int lane = tid & 63;
  const int m16 = lane & 15, q = lane >> 4;
  const int r0 = blockIdx.x * 64 + w * 16;

  f32x4 acc[8];
#pragma unroll
  for (int nt = 0; nt < 8; ++nt) acc[nt] = (f32x4){0.f, 0.f, 0.f, 0.f};

  for (int c2 = 0; c2 < 4; ++c2) {
    int row = min(r0 + m16, N - 1);
    const float* p = aggH + (size_t)row * DD + c2 * 32 + q * 8;
    float4 v0 = *(const float4*)p;
    float4 v1 = *(const float4*)(p + 4);
    float f[8] = {v0.x, v0.y, v0.z, v0.w, v1.x, v1.y, v1.z, v1.w};
    short8 ah, al;
#pragma unroll
    for (int j = 0; j < 8; ++j) { short hi, lo; splitT(f[j], hi, lo); ah[j] = hi; al[j] = lo; }
#pragma unroll
    for (int nt = 0; nt < 8; ++nt) {
      const short* bp = W2F + ((size_t)((c2 * 8 + nt) * 2) * 64 + lane) * 8;
      short8 bh = *(const short8*)bp;
      short8 bl = *(const short8*)(bp + 512);
      acc[nt] = __builtin_amdgcn_mfma_f32_16x16x32_bf16(ah, bh, acc[nt], 0, 0, 0);
      acc[nt] = __builtin_amdgcn_mfma_f32_16x16x32_bf16(al, bh, acc[nt], 0, 0, 0);
      acc[nt] = __builtin_amdgcn_mfma_f32_16x16x32_bf16(ah, bl, acc[nt], 0, 0, 0);
    }
  }

#pragma unroll
  for (int r = 0; r < 4; ++r) {
    int row = r0 + q * 4 + r;
    if (row < N) {
      float av = aggA[row];
#pragma unroll
      for (int nt = 0; nt < 8; ++nt) {
        int col = nt * 16 + m16;
        aggH[(size_t)row * DD + col] = acc[nt][r] + av * msg_b2[col];
      }
    }
  }
}

// ---------------- node update kernel (unchanged, verified) ----------------
__global__ __launch_bounds__(256, 2) void node_mfma_kernel(
    const float* __restrict__ h, const float* __restrict__ agg,
    const short* __restrict__ U1hiT, const short* __restrict__ U1loT,
    const short* __restrict__ U2hiT, const short* __restrict__ U2loT,
    const float* __restrict__ upd_b1, const float* __restrict__ upd_b2,
    const float* __restrict__ g, float* __restrict__ out, int N) {
  __shared__ short smem[29184];
  short* WT1hi = smem;            // 128 cols x 40
  short* WT1lo = smem + 5120;
  short* HIDlo = smem + 10240;
  short* HIDhi = smem + 20480;

  const int tid = threadIdx.x;
  const int wave = tid >> 6;
  const int lane = tid & 63;
  const int m16 = lane & 15;
  const int q = lane >> 4;

  const int n0 = blockIdx.x * 64;
  const int nA = n0 + wave * 16 + m16;
  const int nAc = min(nA, N - 1);

  short8 a1h[8], a1l[8];
  {
    const float* rs = h + (size_t)nAc * DD;
    const float* rd = agg + (size_t)nAc * DD;
#pragma unroll
    for (int t = 0; t < 8; ++t) {
      const float* base = ((t < 4) ? (rs + t * 32) : (rd + (t - 4) * 32)) + q * 8;
      float4 v0 = *(const float4*)(base);
      float4 v1 = *(const float4*)(base + 4);
      float f[8] = {v0.x, v0.y, v0.z, v0.w, v1.x, v1.y, v1.z, v1.w};
      short8 hh, ll;
#pragma unroll
      for (int j = 0; j < 8; ++j) { short hi, lo; split2(f[j], hi, lo); hh[j] = hi; ll[j] = lo; }
      a1h[t] = hh; a1l[t] = ll;
    }
  }

  f32x4 acc[8];
#pragma unroll
  for (int n = 0; n < 8; ++n) {
    float b = upd_b1[n * 16 + m16];
    acc[n] = (f32x4){b, b, b, b};
  }

  for (int t = 0; t < 8; ++t) {
    __syncthreads();
#pragma unroll
    for (int r = 0; r < 4; ++r) {
      int idx = tid + 256 * r;
      int comp = idx >> 9;
      int cid = idx & 511;
      int col = cid >> 2, sub = cid & 3;
      const short* gsrc = (comp ? U1loT : U1hiT) + col * 256 + t * 32 + sub * 8;
      short* ldst = (comp ? WT1lo : WT1hi) + col * 40 + sub * 8;
      *(short8*)ldst = *(const short8*)gsrc;
    }
    __syncthreads();
#pragma unroll
    for (int n = 0; n < 8; ++n) {
      const short* bp = WT1hi + (n * 16 + m16) * 40 + q * 8;
      short8 bh = *(const short8*)bp;
      short8 bl = *(const short8*)(bp + 5120);
      acc[n] = __builtin_amdgcn_mfma_f32_16x16x32_bf16(a1h[t], bh, acc[n], 0, 0, 0);
      acc[n] = __builtin_amdgcn_mfma_f32_16x16x32_bf16(a1l[t], bh, acc[n], 0, 0, 0);
      acc[n] = __builtin_amdgcn_mfma_f32_16x16x32_bf16(a1h[t], bl, acc[n], 0, 0, 0);
    }
  }

  __syncthreads();
#pragma unroll
  for (int n = 0; n < 8; ++n) {
    int col = n * 16 + m16;
#pragma unroll
    for (int r = 0; r < 4; ++r) {
      int row = wave * 16 + q * 4 + r;
      float v = fmaxf(acc[n][r], 0.f);
      short hi, lo; split2(v, hi, lo);
      HIDhi[row * 136 + col] = hi;
      HIDlo[row * 136 + col] = lo;
    }
  }
  __syncthreads();

  short8 a2h[4], a2l[4];
  {
    int mrow = wave * 16 + m16;
#pragma unroll
    for (int t = 0; t < 4; ++t) {
      a2h[t] = *(const short8*)(HIDhi + mrow * 136 + t * 32 + q * 8);
      a2l[t] = *(const short8*)(HIDlo + mrow * 136 + t * 32 + q * 8);
    }
  }

  f32x4 acc2[8];
#pragma unroll
  for (int n = 0; n < 8; ++n) {
    float b = upd_b2[n * 16 + m16];
    acc2[n] = (f32x4){b, b, b, b};
  }

  for (int t = 0; t < 4; ++t) {
    __syncthreads();
#pragma unroll
    for (int r = 0; r < 4; ++r) {
      int idx = tid + 256 * r;
      int comp = idx >> 9;
      int cid = idx & 511;
      int col = cid >> 2, sub = cid & 3;
      const short* gsrc = (comp ? U2loT : U2hiT) + col * 128 + t * 32 + sub * 8;
      short* ldst = (comp ? WT1lo : WT1hi) + col * 40 + sub * 8;
      *(short8*)ldst = *(const short8*)gsrc;
    }
    __syncthreads();
#pragma unroll
    for (int n = 0; n < 8; ++n) {
      const short* bp = WT1hi + (n * 16 + m16) * 40 + q * 8;
      short8 bh = *(const short8*)bp;
      short8 bl = *(const short8*)(bp + 5120);
      acc2[n] = __builtin_amdgcn_mfma_f32_16x16x32_bf16(a2h[t], bh, acc2[n], 0, 0, 0);
      acc2[n] = __builtin_amdgcn_mfma_f32_16x16x32_bf16(a2l[t], bh, acc2[n], 0, 0, 0);
      acc2[n] = __builtin_amdgcn_mfma_f32_16x16x32_bf16(a2h[t], bl, acc2[n], 0, 0, 0);
    }
  }

#pragma unroll
  for (int r = 0; r < 4; ++r) {
    int rowN = n0 + wave * 16 + q * 4 + r;
    if (rowN < N) {
#pragma unroll
      for (int n = 0; n < 8; ++n) {
        int col = n * 16 + m16;
        out[(size_t)rowN * DD + col] = acc2[n][r] + h[(size_t)rowN * DD + col] + g[col];
      }
    }
  }
}

extern "C" void kernel_launch(void* const* d_in, const int* in_sizes, int n_in,
                              void* d_out, int out_size, void* d_ws, size_t ws_size,
                              hipStream_t stream) {
  const float* x = (const float*)d_in[0];
  const int* ei = (const int*)d_in[1];
  const float* msg_W1 = (const float*)d_in[2];
  const float* msg_b1 = (const float*)d_in[3];
  const float* msg_W2 = (const float*)d_in[4];
  const float* msg_b2 = (const float*)d_in[5];
  const float* upd_W1 = (const float*)d_in[6];
  const float* upd_b1 = (const float*)d_in[7];
  const float* upd_W2 = (const float*)d_in[8];
  const float* upd_b2 = (const float*)d_in[9];
  const float* att_W1 = (const float*)d_in[10];
  const float* att_b1 = (const float*)d_in[11];
  const float* att_W2 = (const float*)d_in[12];
  const float* att_b2 = (const float*)d_in[13];
  const float* glb_W = (const float*)d_in[14];
  const float* glb_b = (const float*)d_in[15];

  const int N = in_sizes[0] / DD;
  const int E = in_sizes[1] / 2;
  const int* src = ei;
  const int* dst = ei + E;

  float* out = (float*)d_out;
  float* aggH = (float*)d_ws;                  // N*128 f32
  float* aggA = aggH + (size_t)N * DD;         // N
  float* colsum = aggA + N;                    // 128
  float* g = colsum + DD;                      // 128
  short* WbigF = (short*)(g + DD);             // 131072 shorts
  short* W2F = WbigF + 131072;                 // 32768
  short* U1hiT = W2F + 32768;                  // 32768
  short* U1loT = U1hiT + 32768;                // 32768
  short* U2hiT = U1loT + 32768;                // 16384
  short* U2loT = U2hiT + 16384;                // 16384
  int* rowptr = (int*)(U2loT + 16384);         // N+1 ints (padded to mult of 4)
  int* sortedSrc = rowptr + ((N + 1 + 3) & ~3);  // E ints (padded)
  float* Z = (float*)(sortedSrc + ((E + 3) & ~3));  // N*512 f32
  int* cursor = (int*)aggH;                    // overlay: only used during sort phase

  conv_kernel<<<272, 256, 0, stream>>>(msg_W1, att_W1, msg_W2, upd_W1, upd_W2,
                                       WbigF, W2F, U1hiT, U1loT, U2hiT, U2loT);
  zero128_kernel<<<1, 128, 0, stream>>>(colsum);
  colsum_kernel<<<256, 256, 0, stream>>>(x, colsum, N);
  glb_kernel<<<1, 128, 0, stream>>>(colsum, glb_W, glb_b, g, 1.0f / (float)N);

  // CSR build (edges identical both steps -> sort once per launch)
  hipMemsetAsync(rowptr, 0, (size_t)(N + 1) * sizeof(int), stream);
  hist_kernel<<<1024, 256, 0, stream>>>(dst, rowptr, E);
  scan_kernel<<<1, 1024, 0, stream>>>(rowptr, N + 1);
  hipMemcpyAsync(cursor, rowptr, (size_t)N * sizeof(int), hipMemcpyDeviceToDevice, stream);
  scatter_kernel<<<1024, 256, 0, stream>>>(src, dst, cursor, sortedSrc, E);

  const int zgrid = (N + 31) / 32;
  const int agrid = (N + 7) / 8;
  const int ngrid = (N + 63) / 64;
  for (int step = 0; step < 2; ++step) {
    const float* hptr = (step == 0) ? x : out;
    zprep_kernel<<<zgrid, 256, 0, stream>>>(hptr, WbigF, msg_b1, att_b1, Z, N);
    aggcsr_kernel<<<agrid, 256, 0, stream>>>(Z, rowptr, sortedSrc, att_W2, att_b2,
                                             aggH, aggA, N);
    agggemm_kernel<<<ngrid, 256, 0, stream>>>(aggH, aggA, W2F, msg_b2, N);
    node_mfma_kernel<<<ngrid, 256, 0, stream>>>(hptr, aggH, U1hiT, U1loT, U2hiT, U2loT,
                                                upd_b1, upd_b2, g, out, N);
  }
}

// Round 6
// 588.607 us; speedup vs baseline: 3.6588x; 1.1828x over previous
//
#include <hip/hip_runtime.h>
#include <math.h>

#define DD 128

typedef __attribute__((ext_vector_type(8))) short short8;   // 8 x bf16 bits
typedef __attribute__((ext_vector_type(4))) float f32x4;

__device__ inline short bf16hi(float x) {
  unsigned u = __float_as_uint(x);
  unsigned r = u + 0x7fffu + ((u >> 16) & 1u);  // RTNE
  return (short)(r >> 16);
}
__device__ inline float bf16tof(short h) {
  return __uint_as_float(((unsigned)(unsigned short)h) << 16);
}
__device__ inline void split2(float x, short& hi, short& lo) {  // RTNE
  hi = bf16hi(x);
  float rem = x - bf16tof(hi);
  lo = bf16hi(rem);
}
__device__ inline void splitT(float x, short& hi, short& lo) {  // truncation (cheap)
  unsigned u = __float_as_uint(x);
  hi = (short)(u >> 16);
  float rem = x - __uint_as_float(u & 0xffff0000u);
  lo = (short)(__float_as_uint(rem) >> 16);
}

// ---------------- small helper kernels ----------------
__global__ __launch_bounds__(128) void zero128_kernel(float* p) { p[threadIdx.x] = 0.f; }

__global__ __launch_bounds__(256) void colsum_kernel(const float* __restrict__ x,
                                                     float* __restrict__ colsum, int N) {
  int col = threadIdx.x & 127;
  int part = (blockIdx.x * blockDim.x + threadIdx.x) >> 7;
  int nparts = (gridDim.x * blockDim.x) >> 7;
  float s = 0.f;
  for (int r = part; r < N; r += nparts) s += x[(size_t)r * DD + col];
  atomicAdd(&colsum[col], s);
}

__global__ __launch_bounds__(128) void glb_kernel(const float* __restrict__ colsum,
                                                  const float* __restrict__ glb_W,
                                                  const float* __restrict__ glb_b,
                                                  float* __restrict__ g, float invN) {
  __shared__ float m[DD];
  int j = threadIdx.x;
  m[j] = colsum[j] * invN;
  __syncthreads();
  float s = glb_b[j];
#pragma unroll 8
  for (int k = 0; k < DD; ++k) s = fmaf(m[k], glb_W[k * DD + j], s);
  g[j] = fmaxf(s, 0.f);
}

// W2U = msg_W2 @ upd_W1[128:256] (128x128), v2 = msg_b2 @ upd_W1[128:256] (128)
__global__ __launch_bounds__(256) void wprep_kernel(const float* __restrict__ msg_W2,
                                                    const float* __restrict__ msg_b2,
                                                    const float* __restrict__ upd_W1,
                                                    float* __restrict__ W2U,
                                                    float* __restrict__ v2) {
  int o = blockIdx.x * 256 + threadIdx.x;
  if (o < 16384) {
    int r = o >> 7, c = o & 127;
    float s = 0.f;
#pragma unroll 8
    for (int j = 0; j < 128; ++j) s = fmaf(msg_W2[r * 128 + j], upd_W1[(128 + j) * 128 + c], s);
    W2U[o] = s;
  } else if (o < 16512) {
    int c = o - 16384;
    float s = 0.f;
#pragma unroll 8
    for (int j = 0; j < 128; ++j) s = fmaf(msg_b2[j], upd_W1[(128 + j) * 128 + c], s);
    v2[c] = s;
  }
}

// ---------------- CSR build: histogram -> parallel scan -> scatter ----------------
__global__ __launch_bounds__(256) void hist_kernel(const int* __restrict__ dst,
                                                   int* __restrict__ rowptr, int E) {
  for (int e = blockIdx.x * blockDim.x + threadIdx.x; e < E; e += gridDim.x * blockDim.x)
    atomicAdd(&rowptr[dst[e] + 1], 1);
}

__global__ __launch_bounds__(1024) void scan1_kernel(int* __restrict__ a,
                                                     int* __restrict__ bsum, int n) {
  __shared__ int buf[1024];
  const int tid = threadIdx.x;
  int i = blockIdx.x * 1024 + tid;
  buf[tid] = (i < n) ? a[i] : 0;
  __syncthreads();
#pragma unroll
  for (int off = 1; off < 1024; off <<= 1) {
    int t = (tid >= off) ? buf[tid - off] : 0;
    __syncthreads();
    buf[tid] += t;
    __syncthreads();
  }
  if (i < n) a[i] = buf[tid];
  if (tid == 1023) bsum[blockIdx.x] = buf[1023];
}

__global__ __launch_bounds__(1024) void scan2_kernel(int* __restrict__ a, int n) {
  __shared__ int buf[1024];
  const int tid = threadIdx.x;
  buf[tid] = (tid < n) ? a[tid] : 0;
  __syncthreads();
#pragma unroll
  for (int off = 1; off < 1024; off <<= 1) {
    int t = (tid >= off) ? buf[tid - off] : 0;
    __syncthreads();
    buf[tid] += t;
    __syncthreads();
  }
  if (tid < n) a[tid] = buf[tid];
}

__global__ __launch_bounds__(1024) void scan3_kernel(int* __restrict__ a,
                                                     const int* __restrict__ bsum, int n) {
  int b = blockIdx.x + 1;
  int i = b * 1024 + threadIdx.x;
  if (i < n) a[i] += bsum[b - 1];
}

__global__ __launch_bounds__(256) void scatter_kernel(const int* __restrict__ src,
                                                      const int* __restrict__ dst,
                                                      int* __restrict__ cursor,
                                                      int* __restrict__ sortedSrc, int E) {
  for (int e = blockIdx.x * blockDim.x + threadIdx.x; e < E; e += gridDim.x * blockDim.x) {
    int pos = atomicAdd(&cursor[dst[e]], 1);
    sortedSrc[pos] = src[e];
  }
}

// ---------------- weight prep (frag-major hi/lo + col-major planes) ----------------
// WbigF: frag-major for Z-prep (cols: [msgW1top|attW1top|msgW1bot|attW1bot]).
// U1eff: rows 0..127 = upd_W1 top; rows 128..255 = W2U (W2 folded).  U2: upd_W2.
__global__ __launch_bounds__(256) void conv_kernel(
    const float* __restrict__ msg_W1, const float* __restrict__ att_W1,
    const float* __restrict__ upd_W1, const float* __restrict__ upd_W2,
    const float* __restrict__ W2U,
    short* __restrict__ WbigF,
    short* __restrict__ U1hiT, short* __restrict__ U1loT,
    short* __restrict__ U2hiT, short* __restrict__ U2loT) {
  int i = blockIdx.x * 256 + threadIdx.x;  // 0 .. 65535
  if (i < 16384) {
    int lane = i & 63, p = (i >> 6) & 1, n = (i >> 7) & 31, c = i >> 12;
    int col = n * 16 + (lane & 15);
#pragma unroll
    for (int j = 0; j < 8; ++j) {
      int k = c * 32 + ((lane >> 4) & 3) * 8 + j;
      float v;
      if (col < 128)      v = msg_W1[k * 128 + col];
      else if (col < 256) v = att_W1[k * 128 + (col - 128)];
      else if (col < 384) v = msg_W1[(k + 128) * 128 + (col - 256)];
      else                v = att_W1[(k + 128) * 128 + (col - 384)];
      short hi, lo; splitT(v, hi, lo);
      WbigF[(size_t)i * 8 + j] = p ? lo : hi;
    }
  } else if (i < 49152) {
    int j = i - 16384;  // col 0..127, k 0..255
    int col = j & 127, k = j >> 7;
    float v = (k < 128) ? upd_W1[k * 128 + col] : W2U[(k - 128) * 128 + col];
    short hi, lo; split2(v, hi, lo);
    U1hiT[col * 256 + k] = hi; U1loT[col * 256 + k] = lo;
  } else {
    int j = i - 49152;
    int col = j & 127, k = (j >> 7) & 127;
    float v = upd_W2[k * 128 + col];
    short hi, lo; split2(v, hi, lo);
    U2hiT[col * 128 + k] = hi; U2loT[col * 128 + k] = lo;
  }
}

// ---------------- Z-prep GEMM: Z[N x 512] = h @ Wbig (+ [msg_b1|att_b1|0|0]) ----
__global__ __launch_bounds__(256, 2) void zprep_kernel(
    const float* __restrict__ h, const short* __restrict__ WbigF,
    const float* __restrict__ msg_b1, const float* __restrict__ att_b1,
    float* __restrict__ Z, int N) {
  const int tid = threadIdx.x;
  const int w = tid >> 6;
  const int lane = tid & 63;
  const int m16 = lane & 15, q = lane >> 4;
  const int r0 = blockIdx.x * 32;

  f32x4 acc[2][8];
#pragma unroll
  for (int nt = 0; nt < 8; ++nt) {
    int col = w * 128 + nt * 16 + m16;
    float b = (col < 128) ? msg_b1[col] : ((col < 256) ? att_b1[col - 128] : 0.f);
    acc[0][nt] = (f32x4){b, b, b, b};
    acc[1][nt] = (f32x4){b, b, b, b};
  }

  for (int c = 0; c < 4; ++c) {
    short8 ah[2], al[2];
#pragma unroll
    for (int mt = 0; mt < 2; ++mt) {
      int row = min(r0 + mt * 16 + m16, N - 1);
      const float* p = h + (size_t)row * DD + c * 32 + q * 8;
      float4 v0 = *(const float4*)p;
      float4 v1 = *(const float4*)(p + 4);
      float f[8] = {v0.x, v0.y, v0.z, v0.w, v1.x, v1.y, v1.z, v1.w};
#pragma unroll
      for (int j = 0; j < 8; ++j) { short hi, lo; splitT(f[j], hi, lo); ah[mt][j] = hi; al[mt][j] = lo; }
    }
#pragma unroll
    for (int nt = 0; nt < 8; ++nt) {
      int ng = w * 8 + nt;
      const short* bp = WbigF + ((size_t)((c * 32 + ng) * 2) * 64 + lane) * 8;
      short8 bh = *(const short8*)bp;
      short8 bl = *(const short8*)(bp + 512);
#pragma unroll
      for (int mt = 0; mt < 2; ++mt) {
        acc[mt][nt] = __builtin_amdgcn_mfma_f32_16x16x32_bf16(ah[mt], bh, acc[mt][nt], 0, 0, 0);
        acc[mt][nt] = __builtin_amdgcn_mfma_f32_16x16x32_bf16(al[mt], bh, acc[mt][nt], 0, 0, 0);
        acc[mt][nt] = __builtin_amdgcn_mfma_f32_16x16x32_bf16(ah[mt], bl, acc[mt][nt], 0, 0, 0);
      }
    }
  }

#pragma unroll
  for (int mt = 0; mt < 2; ++mt)
#pragma unroll
    for (int r = 0; r < 4; ++r) {
      int row = r0 + mt * 16 + q * 4 + r;
      if (row < N) {
#pragma unroll
        for (int nt = 0; nt < 8; ++nt) {
          int col = w * 128 + nt * 16 + m16;
          Z[(size_t)row * 512 + col] = acc[mt][nt][r];
        }
      }
    }
}

// ---------------- CSR aggregation (no atomics, 4-wide unroll) ----------------
__global__ __launch_bounds__(256) void aggcsr_kernel(
    const float* __restrict__ Z, const int* __restrict__ rowptr,
    const int* __restrict__ sortedSrc, const float* __restrict__ att_W2,
    const float* __restrict__ att_b2, float* __restrict__ aggH,
    float* __restrict__ aggA, int N) {
  const int node = blockIdx.x * 8 + (threadIdx.x >> 5);
  const int c = threadIdx.x & 31;
  if (node >= N) return;

  const float4 aw = *(const float4*)(att_W2 + 4 * c);
  const float ab2 = att_b2[0];
  const float* Zn = Z + (size_t)node * 512;
  const float4 dm = *(const float4*)(Zn + 256 + 4 * c);
  const float4 da = *(const float4*)(Zn + 384 + 4 * c);

  float aH0 = 0.f, aH1 = 0.f, aH2 = 0.f, aH3 = 0.f, aA = 0.f;
  const int b = rowptr[node], e = rowptr[node + 1];

  int i = b;
  for (; i + 3 < e; i += 4) {
    int s0 = sortedSrc[i], s1 = sortedSrc[i + 1], s2 = sortedSrc[i + 2], s3 = sortedSrc[i + 3];
    const float* Z0 = Z + (size_t)s0 * 512 + 4 * c;
    const float* Z1 = Z + (size_t)s1 * 512 + 4 * c;
    const float* Z2 = Z + (size_t)s2 * 512 + 4 * c;
    const float* Z3 = Z + (size_t)s3 * 512 + 4 * c;
    float4 sm0 = *(const float4*)Z0, sa0 = *(const float4*)(Z0 + 128);
    float4 sm1 = *(const float4*)Z1, sa1 = *(const float4*)(Z1 + 128);
    float4 sm2 = *(const float4*)Z2, sa2 = *(const float4*)(Z2 + 128);
    float4 sm3 = *(const float4*)Z3, sa3 = *(const float4*)(Z3 + 128);

    float h0[4], h1[4], h2[4], h3[4];
    h0[0] = fmaxf(sm0.x + dm.x, 0.f); h0[1] = fmaxf(sm0.y + dm.y, 0.f);
    h0[2] = fmaxf(sm0.z + dm.z, 0.f); h0[3] = fmaxf(sm0.w + dm.w, 0.f);
    h1[0] = fmaxf(sm1.x + dm.x, 0.f); h1[1] = fmaxf(sm1.y + dm.y, 0.f);
    h1[2] = fmaxf(sm1.z + dm.z, 0.f); h1[3] = fmaxf(sm1.w + dm.w, 0.f);
    h2[0] = fmaxf(sm2.x + dm.x, 0.f); h2[1] = fmaxf(sm2.y + dm.y, 0.f);
    h2[2] = fmaxf(sm2.z + dm.z, 0.f); h2[3] = fmaxf(sm2.w + dm.w, 0.f);
    h3[0] = fmaxf(sm3.x + dm.x, 0.f); h3[1] = fmaxf(sm3.y + dm.y, 0.f);
    h3[2] = fmaxf(sm3.z + dm.z, 0.f); h3[3] = fmaxf(sm3.w + dm.w, 0.f);

    float p0 = fmaf(fmaxf(sa0.x + da.x, 0.f), aw.x,
               fmaf(fmaxf(sa0.y + da.y, 0.f), aw.y,
               fmaf(fmaxf(sa0.z + da.z, 0.f), aw.z, fmaxf(sa0.w + da.w, 0.f) * aw.w)));
    float p1 = fmaf(fmaxf(sa1.x + da.x, 0.f), aw.x,
               fmaf(fmaxf(sa1.y + da.y, 0.f), aw.y,
               fmaf(fmaxf(sa1.z + da.z, 0.f), aw.z, fmaxf(sa1.w + da.w, 0.f) * aw.w)));
    float p2 = fmaf(fmaxf(sa2.x + da.x, 0.f), aw.x,
               fmaf(fmaxf(sa2.y + da.y, 0.f), aw.y,
               fmaf(fmaxf(sa2.z + da.z, 0.f), aw.z, fmaxf(sa2.w + da.w, 0.f) * aw.w)));
    float p3 = fmaf(fmaxf(sa3.x + da.x, 0.f), aw.x,
               fmaf(fmaxf(sa3.y + da.y, 0.f), aw.y,
               fmaf(fmaxf(sa3.z + da.z, 0.f), aw.z, fmaxf(sa3.w + da.w, 0.f) * aw.w)));
#pragma unroll
    for (int off = 1; off < 32; off <<= 1) {
      p0 += __shfl_xor(p0, off);
      p1 += __shfl_xor(p1, off);
      p2 += __shfl_xor(p2, off);
      p3 += __shfl_xor(p3, off);
    }
    float t0 = 1.f / (1.f + expf(-(p0 + ab2)));
    float t1 = 1.f / (1.f + expf(-(p1 + ab2)));
    float t2 = 1.f / (1.f + expf(-(p2 + ab2)));
    float t3 = 1.f / (1.f + expf(-(p3 + ab2)));
    aA += (t0 + t1) + (t2 + t3);
    aH0 = fmaf(t0, h0[0], fmaf(t1, h1[0], fmaf(t2, h2[0], fmaf(t3, h3[0], aH0))));
    aH1 = fmaf(t0, h0[1], fmaf(t1, h1[1], fmaf(t2, h2[1], fmaf(t3, h3[1], aH1))));
    aH2 = fmaf(t0, h0[2], fmaf(t1, h1[2], fmaf(t2, h2[2], fmaf(t3, h3[2], aH2))));
    aH3 = fmaf(t0, h0[3], fmaf(t1, h1[3], fmaf(t2, h2[3], fmaf(t3, h3[3], aH3))));
  }
  for (; i < e; ++i) {
    int s0 = sortedSrc[i];
    const float* Z0 = Z + (size_t)s0 * 512 + 4 * c;
    float4 sm0 = *(const float4*)Z0;
    float4 sa0 = *(const float4*)(Z0 + 128);
    float h00 = fmaxf(sm0.x + dm.x, 0.f), h01 = fmaxf(sm0.y + dm.y, 0.f);
    float h02 = fmaxf(sm0.z + dm.z, 0.f), h03 = fmaxf(sm0.w + dm.w, 0.f);
    float p0 = fmaf(fmaxf(sa0.x + da.x, 0.f), aw.x,
               fmaf(fmaxf(sa0.y + da.y, 0.f), aw.y,
               fmaf(fmaxf(sa0.z + da.z, 0.f), aw.z, fmaxf(sa0.w + da.w, 0.f) * aw.w)));
#pragma unroll
    for (int off = 1; off < 32; off <<= 1) p0 += __shfl_xor(p0, off);
    float t0 = 1.f / (1.f + expf(-(p0 + ab2)));
    aA += t0;
    aH0 = fmaf(t0, h00, aH0);
    aH1 = fmaf(t0, h01, aH1);
    aH2 = fmaf(t0, h02, aH2);
    aH3 = fmaf(t0, h03, aH3);
  }

  *(float4*)(aggH + (size_t)node * DD + 4 * c) = (float4){aH0, aH1, aH2, aH3};
  if (c == 0) aggA[node] = aA;
}

// ---------------- node update (W2 folded in): ----------------
// out = relu(h@U1top + aggH@W2U + aggA (x) v2 + upd_b1) @ U2 + upd_b2 + h + g
__global__ __launch_bounds__(256, 2) void node_mfma_kernel(
    const float* __restrict__ h, const float* __restrict__ aggH,
    const float* __restrict__ aggA, const float* __restrict__ v2,
    const short* __restrict__ U1hiT, const short* __restrict__ U1loT,
    const short* __restrict__ U2hiT, const short* __restrict__ U2loT,
    const float* __restrict__ upd_b1, const float* __restrict__ upd_b2,
    const float* __restrict__ g, float* __restrict__ out, int N) {
  __shared__ short smem[29184];
  short* WT1hi = smem;            // 128 cols x 40
  short* WT1lo = smem + 5120;
  short* HIDlo = smem + 10240;
  short* HIDhi = smem + 20480;

  const int tid = threadIdx.x;
  const int wave = tid >> 6;
  const int lane = tid & 63;
  const int m16 = lane & 15;
  const int q = lane >> 4;

  const int n0 = blockIdx.x * 64;
  const int nA = n0 + wave * 16 + m16;
  const int nAc = min(nA, N - 1);

  short8 a1h[8], a1l[8];
  {
    const float* rs = h + (size_t)nAc * DD;
    const float* rd = aggH + (size_t)nAc * DD;
#pragma unroll
    for (int t = 0; t < 8; ++t) {
      const float* base = ((t < 4) ? (rs + t * 32) : (rd + (t - 4) * 32)) + q * 8;
      float4 v0 = *(const float4*)(base);
      float4 v1 = *(const float4*)(base + 4);
      float f[8] = {v0.x, v0.y, v0.z, v0.w, v1.x, v1.y, v1.z, v1.w};
      short8 hh, ll;
#pragma unroll
      for (int j = 0; j < 8; ++j) { short hi, lo; split2(f[j], hi, lo); hh[j] = hi; ll[j] = lo; }
      a1h[t] = hh; a1l[t] = ll;
    }
  }

  f32x4 acc[8];
#pragma unroll
  for (int n = 0; n < 8; ++n) {
    float b = upd_b1[n * 16 + m16];
    acc[n] = (f32x4){b, b, b, b};
  }

  for (int t = 0; t < 8; ++t) {
    __syncthreads();
#pragma unroll
    for (int r = 0; r < 4; ++r) {
      int idx = tid + 256 * r;
      int comp = idx >> 9;
      int cid = idx & 511;
      int col = cid >> 2, sub = cid & 3;
      const short* gsrc = (comp ? U1loT : U1hiT) + col * 256 + t * 32 + sub * 8;
      short* ldst = (comp ? WT1lo : WT1hi) + col * 40 + sub * 8;
      *(short8*)ldst = *(const short8*)gsrc;
    }
    __syncthreads();
#pragma unroll
    for (int n = 0; n < 8; ++n) {
      const short* bp = WT1hi + (n * 16 + m16) * 40 + q * 8;
      short8 bh = *(const short8*)bp;
      short8 bl = *(const short8*)(bp + 5120);
      acc[n] = __builtin_amdgcn_mfma_f32_16x16x32_bf16(a1h[t], bh, acc[n], 0, 0, 0);
      acc[n] = __builtin_amdgcn_mfma_f32_16x16x32_bf16(a1l[t], bh, acc[n], 0, 0, 0);
      acc[n] = __builtin_amdgcn_mfma_f32_16x16x32_bf16(a1h[t], bl, acc[n], 0, 0, 0);
    }
  }

  // fold in aggA (x) v2
  {
    float aAv[4];
#pragma unroll
    for (int r = 0; r < 4; ++r) aAv[r] = aggA[min(n0 + wave * 16 + q * 4 + r, N - 1)];
#pragma unroll
    for (int n = 0; n < 8; ++n) {
      float vv = v2[n * 16 + m16];
#pragma unroll
      for (int r = 0; r < 4; ++r) acc[n][r] = fmaf(aAv[r], vv, acc[n][r]);
    }
  }

  __syncthreads();
#pragma unroll
  for (int n = 0; n < 8; ++n) {
    int col = n * 16 + m16;
#pragma unroll
    for (int r = 0; r < 4; ++r) {
      int row = wave * 16 + q * 4 + r;
      float v = fmaxf(acc[n][r], 0.f);
      short hi, lo; split2(v, hi, lo);
      HIDhi[row * 136 + col] = hi;
      HIDlo[row * 136 + col] = lo;
    }
  }
  __syncthreads();

  short8 a2h[4], a2l[4];
  {
    int mrow = wave * 16 + m16;
#pragma unroll
    for (int t = 0; t < 4; ++t) {
      a2h[t] = *(const short8*)(HIDhi + mrow * 136 + t * 32 + q * 8);
      a2l[t] = *(const short8*)(HIDlo + mrow * 136 + t * 32 + q * 8);
    }
  }

  f32x4 acc2[8];
#pragma unroll
  for (int n = 0; n < 8; ++n) {
    float b = upd_b2[n * 16 + m16];
    acc2[n] = (f32x4){b, b, b, b};
  }

  for (int t = 0; t < 4; ++t) {
    __syncthreads();
#pragma unroll
    for (int r = 0; r < 4; ++r) {
      int idx = tid + 256 * r;
      int comp = idx >> 9;
      int cid = idx & 511;
      int col = cid >> 2, sub = cid & 3;
      const short* gsrc = (comp ? U2loT : U2hiT) + col * 128 + t * 32 + sub * 8;
      short* ldst = (comp ? WT1lo : WT1hi) + col * 40 + sub * 8;
      *(short8*)ldst = *(const short8*)gsrc;
    }
    __syncthreads();
#pragma unroll
    for (int n = 0; n < 8; ++n) {
      const short* bp = WT1hi + (n * 16 + m16) * 40 + q * 8;
      short8 bh = *(const short8*)bp;
      short8 bl = *(const short8*)(bp + 5120);
      acc2[n] = __builtin_amdgcn_mfma_f32_16x16x32_bf16(a2h[t], bh, acc2[n], 0, 0, 0);
      acc2[n] = __builtin_amdgcn_mfma_f32_16x16x32_bf16(a2l[t], bh, acc2[n], 0, 0, 0);
      acc2[n] = __builtin_amdgcn_mfma_f32_16x16x32_bf16(a2h[t], bl, acc2[n], 0, 0, 0);
    }
  }

#pragma unroll
  for (int r = 0; r < 4; ++r) {
    int rowN = n0 + wave * 16 + q * 4 + r;
    if (rowN < N) {
#pragma unroll
      for (int n = 0; n < 8; ++n) {
        int col = n * 16 + m16;
        out[(size_t)rowN * DD + col] = acc2[n][r] + h[(size_t)rowN * DD + col] + g[col];
      }
    }
  }
}

extern "C" void kernel_launch(void* const* d_in, const int* in_sizes, int n_in,
                              void* d_out, int out_size, void* d_ws, size_t ws_size,
                              hipStream_t stream) {
  const float* x = (const float*)d_in[0];
  const int* ei = (const int*)d_in[1];
  const float* msg_W1 = (const float*)d_in[2];
  const float* msg_b1 = (const float*)d_in[3];
  const float* msg_W2 = (const float*)d_in[4];
  const float* msg_b2 = (const float*)d_in[5];
  const float* upd_W1 = (const float*)d_in[6];
  const float* upd_b1 = (const float*)d_in[7];
  const float* upd_W2 = (const float*)d_in[8];
  const float* upd_b2 = (const float*)d_in[9];
  const float* att_W1 = (const float*)d_in[10];
  const float* att_b1 = (const float*)d_in[11];
  const float* att_W2 = (const float*)d_in[12];
  const float* att_b2 = (const float*)d_in[13];
  const float* glb_W = (const float*)d_in[14];
  const float* glb_b = (const float*)d_in[15];

  const int N = in_sizes[0] / DD;
  const int E = in_sizes[1] / 2;
  const int* src = ei;
  const int* dst = ei + E;

  float* out = (float*)d_out;
  float* aggH = (float*)d_ws;                  // N*128 f32
  float* aggA = aggH + (size_t)N * DD;         // N
  float* colsum = aggA + N;                    // 128
  float* g = colsum + DD;                      // 128
  float* W2U = g + DD;                         // 16384 f32
  float* v2 = W2U + 16384;                     // 128 f32
  short* WbigF = (short*)(v2 + DD);            // 131072 shorts
  short* U1hiT = WbigF + 131072;               // 32768
  short* U1loT = U1hiT + 32768;                // 32768
  short* U2hiT = U1loT + 32768;                // 16384
  short* U2loT = U2hiT + 16384;                // 16384
  int* bsum = (int*)(U2loT + 16384);           // 64 ints
  int* rowptr = bsum + 64;                     // N+1 ints
  int* sortedSrc = rowptr + ((N + 1 + 3) & ~3);
  float* Z = (float*)(sortedSrc + ((E + 3) & ~3));  // N*512 f32
  int* cursor = (int*)aggH;                    // overlay during sort phase only

  wprep_kernel<<<65, 256, 0, stream>>>(msg_W2, msg_b2, upd_W1, W2U, v2);
  conv_kernel<<<256, 256, 0, stream>>>(msg_W1, att_W1, upd_W1, upd_W2, W2U,
                                       WbigF, U1hiT, U1loT, U2hiT, U2loT);
  zero128_kernel<<<1, 128, 0, stream>>>(colsum);
  colsum_kernel<<<256, 256, 0, stream>>>(x, colsum, N);
  glb_kernel<<<1, 128, 0, stream>>>(colsum, glb_W, glb_b, g, 1.0f / (float)N);

  // CSR build (edges identical both steps -> sort once per launch)
  hipMemsetAsync(rowptr, 0, (size_t)(N + 1) * sizeof(int), stream);
  hist_kernel<<<1024, 256, 0, stream>>>(dst, rowptr, E);
  const int nscan = N + 1;
  const int nb = (nscan + 1023) / 1024;
  scan1_kernel<<<nb, 1024, 0, stream>>>(rowptr, bsum, nscan);
  scan2_kernel<<<1, 1024, 0, stream>>>(bsum, nb);
  if (nb > 1) scan3_kernel<<<nb - 1, 1024, 0, stream>>>(rowptr, bsum, nscan);
  hipMemcpyAsync(cursor, rowptr, (size_t)N * sizeof(int), hipMemcpyDeviceToDevice, stream);
  scatter_kernel<<<1024, 256, 0, stream>>>(src, dst, cursor, sortedSrc, E);

  const int zgrid = (N + 31) / 32;
  const int agrid = (N + 7) / 8;
  const int ngrid = (N + 63) / 64;
  for (int step = 0; step < 2; ++step) {
    const float* hptr = (step == 0) ? x : out;
    zprep_kernel<<<zgrid, 256, 0, stream>>>(hptr, WbigF, msg_b1, att_b1, Z, N);
    aggcsr_kernel<<<agrid, 256, 0, stream>>>(Z, rowptr, sortedSrc, att_W2, att_b2,
                                             aggH, aggA, N);
    node_mfma_kernel<<<ngrid, 256, 0, stream>>>(hptr, aggH, aggA, v2,
                                                U1hiT, U1loT, U2hiT, U2loT,
                                                upd_b1, upd_b2, g, out, N);
  }
}

// Round 7
// 507.935 us; speedup vs baseline: 4.2399x; 1.1588x over previous
//
#include <hip/hip_runtime.h>
#include <math.h>

#define DD 128

typedef __attribute__((ext_vector_type(8))) short short8;   // 8 x bf16 bits
typedef __attribute__((ext_vector_type(4))) float f32x4;
typedef __attribute__((ext_vector_type(4))) _Float16 f16x4;

__device__ inline short bf16hi(float x) {
  unsigned u = __float_as_uint(x);
  unsigned r = u + 0x7fffu + ((u >> 16) & 1u);  // RTNE
  return (short)(r >> 16);
}
__device__ inline float bf16tof(short h) {
  return __uint_as_float(((unsigned)(unsigned short)h) << 16);
}
__device__ inline void split2(float x, short& hi, short& lo) {  // RTNE
  hi = bf16hi(x);
  float rem = x - bf16tof(hi);
  lo = bf16hi(rem);
}
__device__ inline void splitT(float x, short& hi, short& lo) {  // truncation (cheap)
  unsigned u = __float_as_uint(x);
  hi = (short)(u >> 16);
  float rem = x - __uint_as_float(u & 0xffff0000u);
  lo = (short)(__float_as_uint(rem) >> 16);
}

// ---------------- small helper kernels ----------------
__global__ __launch_bounds__(128) void zero128_kernel(float* p) { p[threadIdx.x] = 0.f; }

__global__ __launch_bounds__(256) void colsum_kernel(const float* __restrict__ x,
                                                     float* __restrict__ colsum, int N) {
  int col = threadIdx.x & 127;
  int part = (blockIdx.x * blockDim.x + threadIdx.x) >> 7;
  int nparts = (gridDim.x * blockDim.x) >> 7;
  float s = 0.f;
  for (int r = part; r < N; r += nparts) s += x[(size_t)r * DD + col];
  atomicAdd(&colsum[col], s);
}

__global__ __launch_bounds__(128) void glb_kernel(const float* __restrict__ colsum,
                                                  const float* __restrict__ glb_W,
                                                  const float* __restrict__ glb_b,
                                                  float* __restrict__ g, float invN) {
  __shared__ float m[DD];
  int j = threadIdx.x;
  m[j] = colsum[j] * invN;
  __syncthreads();
  float s = glb_b[j];
#pragma unroll 8
  for (int k = 0; k < DD; ++k) s = fmaf(m[k], glb_W[k * DD + j], s);
  g[j] = fmaxf(s, 0.f);
}

// W2U = msg_W2 @ upd_W1[128:256] (128x128), v2 = msg_b2 @ upd_W1[128:256] (128)
__global__ __launch_bounds__(256) void wprep_kernel(const float* __restrict__ msg_W2,
                                                    const float* __restrict__ msg_b2,
                                                    const float* __restrict__ upd_W1,
                                                    float* __restrict__ W2U,
                                                    float* __restrict__ v2) {
  int o = blockIdx.x * 256 + threadIdx.x;
  if (o < 16384) {
    int r = o >> 7, c = o & 127;
    float s = 0.f;
#pragma unroll 8
    for (int j = 0; j < 128; ++j) s = fmaf(msg_W2[r * 128 + j], upd_W1[(128 + j) * 128 + c], s);
    W2U[o] = s;
  } else if (o < 16512) {
    int c = o - 16384;
    float s = 0.f;
#pragma unroll 8
    for (int j = 0; j < 128; ++j) s = fmaf(msg_b2[j], upd_W1[(128 + j) * 128 + c], s);
    v2[c] = s;
  }
}

// ---------------- CSR build: histogram -> parallel scan -> scatter ----------------
__global__ __launch_bounds__(256) void hist_kernel(const int* __restrict__ dst,
                                                   int* __restrict__ rowptr, int E) {
  for (int e = blockIdx.x * blockDim.x + threadIdx.x; e < E; e += gridDim.x * blockDim.x)
    atomicAdd(&rowptr[dst[e] + 1], 1);
}

__global__ __launch_bounds__(1024) void scan1_kernel(int* __restrict__ a,
                                                     int* __restrict__ bsum, int n) {
  __shared__ int buf[1024];
  const int tid = threadIdx.x;
  int i = blockIdx.x * 1024 + tid;
  buf[tid] = (i < n) ? a[i] : 0;
  __syncthreads();
#pragma unroll
  for (int off = 1; off < 1024; off <<= 1) {
    int t = (tid >= off) ? buf[tid - off] : 0;
    __syncthreads();
    buf[tid] += t;
    __syncthreads();
  }
  if (i < n) a[i] = buf[tid];
  if (tid == 1023) bsum[blockIdx.x] = buf[1023];
}

__global__ __launch_bounds__(1024) void scan2_kernel(int* __restrict__ a, int n) {
  __shared__ int buf[1024];
  const int tid = threadIdx.x;
  buf[tid] = (tid < n) ? a[tid] : 0;
  __syncthreads();
#pragma unroll
  for (int off = 1; off < 1024; off <<= 1) {
    int t = (tid >= off) ? buf[tid - off] : 0;
    __syncthreads();
    buf[tid] += t;
    __syncthreads();
  }
  if (tid < n) a[tid] = buf[tid];
}

__global__ __launch_bounds__(1024) void scan3_kernel(int* __restrict__ a,
                                                     const int* __restrict__ bsum, int n) {
  int b = blockIdx.x + 1;
  int i = b * 1024 + threadIdx.x;
  if (i < n) a[i] += bsum[b - 1];
}

__global__ __launch_bounds__(256) void scatter_kernel(const int* __restrict__ src,
                                                      const int* __restrict__ dst,
                                                      int* __restrict__ cursor,
                                                      int* __restrict__ sortedSrc, int E) {
  for (int e = blockIdx.x * blockDim.x + threadIdx.x; e < E; e += gridDim.x * blockDim.x) {
    int pos = atomicAdd(&cursor[dst[e]], 1);
    sortedSrc[pos] = src[e];
  }
}

// ---------------- weight prep (frag-major hi/lo + col-major planes) ----------------
__global__ __launch_bounds__(256) void conv_kernel(
    const float* __restrict__ msg_W1, const float* __restrict__ att_W1,
    const float* __restrict__ upd_W1, const float* __restrict__ upd_W2,
    const float* __restrict__ W2U,
    short* __restrict__ WbigF,
    short* __restrict__ U1hiT, short* __restrict__ U1loT,
    short* __restrict__ U2hiT, short* __restrict__ U2loT) {
  int i = blockIdx.x * 256 + threadIdx.x;  // 0 .. 65535
  if (i < 16384) {
    int lane = i & 63, p = (i >> 6) & 1, n = (i >> 7) & 31, c = i >> 12;
    int col = n * 16 + (lane & 15);
#pragma unroll
    for (int j = 0; j < 8; ++j) {
      int k = c * 32 + ((lane >> 4) & 3) * 8 + j;
      float v;
      if (col < 128)      v = msg_W1[k * 128 + col];
      else if (col < 256) v = att_W1[k * 128 + (col - 128)];
      else if (col < 384) v = msg_W1[(k + 128) * 128 + (col - 256)];
      else                v = att_W1[(k + 128) * 128 + (col - 384)];
      short hi, lo; splitT(v, hi, lo);
      WbigF[(size_t)i * 8 + j] = p ? lo : hi;
    }
  } else if (i < 49152) {
    int j = i - 16384;  // col 0..127, k 0..255
    int col = j & 127, k = j >> 7;
    float v = (k < 128) ? upd_W1[k * 128 + col] : W2U[(k - 128) * 128 + col];
    short hi, lo; split2(v, hi, lo);
    U1hiT[col * 256 + k] = hi; U1loT[col * 256 + k] = lo;
  } else {
    int j = i - 49152;
    int col = j & 127, k = (j >> 7) & 127;
    float v = upd_W2[k * 128 + col];
    short hi, lo; split2(v, hi, lo);
    U2hiT[col * 128 + k] = hi; U2loT[col * 128 + k] = lo;
  }
}

// ---------------- Z-prep GEMM (step 0 only): ----------------
// Zsrc[N x 256] fp16 = h @ Wbig[:,0:256] + [msg_b1|att_b1]
// Zdst[N x 256] fp32 = h @ Wbig[:,256:512]
__global__ __launch_bounds__(256, 2) void zprep_kernel(
    const float* __restrict__ h, const short* __restrict__ WbigF,
    const float* __restrict__ msg_b1, const float* __restrict__ att_b1,
    _Float16* __restrict__ Zsrc, float* __restrict__ Zdst, int N) {
  const int tid = threadIdx.x;
  const int w = tid >> 6;
  const int lane = tid & 63;
  const int m16 = lane & 15, q = lane >> 4;
  const int r0 = blockIdx.x * 32;

  f32x4 acc[2][8];
#pragma unroll
  for (int nt = 0; nt < 8; ++nt) {
    int col = w * 128 + nt * 16 + m16;
    float b = (col < 128) ? msg_b1[col] : ((col < 256) ? att_b1[col - 128] : 0.f);
    acc[0][nt] = (f32x4){b, b, b, b};
    acc[1][nt] = (f32x4){b, b, b, b};
  }

  for (int c = 0; c < 4; ++c) {
    short8 ah[2], al[2];
#pragma unroll
    for (int mt = 0; mt < 2; ++mt) {
      int row = min(r0 + mt * 16 + m16, N - 1);
      const float* p = h + (size_t)row * DD + c * 32 + q * 8;
      float4 v0 = *(const float4*)p;
      float4 v1 = *(const float4*)(p + 4);
      float f[8] = {v0.x, v0.y, v0.z, v0.w, v1.x, v1.y, v1.z, v1.w};
#pragma unroll
      for (int j = 0; j < 8; ++j) { short hi, lo; splitT(f[j], hi, lo); ah[mt][j] = hi; al[mt][j] = lo; }
    }
#pragma unroll
    for (int nt = 0; nt < 8; ++nt) {
      int ng = w * 8 + nt;
      const short* bp = WbigF + ((size_t)((c * 32 + ng) * 2) * 64 + lane) * 8;
      short8 bh = *(const short8*)bp;
      short8 bl = *(const short8*)(bp + 512);
#pragma unroll
      for (int mt = 0; mt < 2; ++mt) {
        acc[mt][nt] = __builtin_amdgcn_mfma_f32_16x16x32_bf16(ah[mt], bh, acc[mt][nt], 0, 0, 0);
        acc[mt][nt] = __builtin_amdgcn_mfma_f32_16x16x32_bf16(al[mt], bh, acc[mt][nt], 0, 0, 0);
        acc[mt][nt] = __builtin_amdgcn_mfma_f32_16x16x32_bf16(ah[mt], bl, acc[mt][nt], 0, 0, 0);
      }
    }
  }

#pragma unroll
  for (int mt = 0; mt < 2; ++mt)
#pragma unroll
    for (int r = 0; r < 4; ++r) {
      int row = r0 + mt * 16 + q * 4 + r;
      if (row < N) {
#pragma unroll
        for (int nt = 0; nt < 8; ++nt) {
          int col = w * 128 + nt * 16 + m16;
          float v = acc[mt][nt][r];
          if (col < 256) Zsrc[(size_t)row * 256 + col] = (_Float16)v;
          else           Zdst[(size_t)row * 256 + (col - 256)] = v;
        }
      }
    }
}

// ---------------- CSR aggregation (no atomics; fp16 src gather) ----------------
__global__ __launch_bounds__(256) void aggcsr_kernel(
    const _Float16* __restrict__ Zsrc, const float* __restrict__ Zdst,
    const int* __restrict__ rowptr, const int* __restrict__ sortedSrc,
    const float* __restrict__ att_W2, const float* __restrict__ att_b2,
    float* __restrict__ aggH, float* __restrict__ aggA, int N) {
  const int node = blockIdx.x * 8 + (threadIdx.x >> 5);
  const int c = threadIdx.x & 31;
  if (node >= N) return;

  const float4 aw = *(const float4*)(att_W2 + 4 * c);
  const float ab2 = att_b2[0];
  const float* Zn = Zdst + (size_t)node * 256;
  const float4 dm = *(const float4*)(Zn + 4 * c);
  const float4 da = *(const float4*)(Zn + 128 + 4 * c);

  float aH0 = 0.f, aH1 = 0.f, aH2 = 0.f, aH3 = 0.f, aA = 0.f;
  const int b = rowptr[node], e = rowptr[node + 1];

  int i = b;
  for (; i + 1 < e; i += 2) {
    int s0 = sortedSrc[i], s1 = sortedSrc[i + 1];
    const _Float16* Z0 = Zsrc + (size_t)s0 * 256 + 4 * c;
    const _Float16* Z1 = Zsrc + (size_t)s1 * 256 + 4 * c;
    f16x4 m0 = *(const f16x4*)Z0, a0 = *(const f16x4*)(Z0 + 128);
    f16x4 m1 = *(const f16x4*)Z1, a1 = *(const f16x4*)(Z1 + 128);

    float h0[4], h1[4];
    h0[0] = fmaxf((float)m0[0] + dm.x, 0.f); h0[1] = fmaxf((float)m0[1] + dm.y, 0.f);
    h0[2] = fmaxf((float)m0[2] + dm.z, 0.f); h0[3] = fmaxf((float)m0[3] + dm.w, 0.f);
    h1[0] = fmaxf((float)m1[0] + dm.x, 0.f); h1[1] = fmaxf((float)m1[1] + dm.y, 0.f);
    h1[2] = fmaxf((float)m1[2] + dm.z, 0.f); h1[3] = fmaxf((float)m1[3] + dm.w, 0.f);

    float p0 = fmaf(fmaxf((float)a0[0] + da.x, 0.f), aw.x,
               fmaf(fmaxf((float)a0[1] + da.y, 0.f), aw.y,
               fmaf(fmaxf((float)a0[2] + da.z, 0.f), aw.z,
                    fmaxf((float)a0[3] + da.w, 0.f) * aw.w)));
    float p1 = fmaf(fmaxf((float)a1[0] + da.x, 0.f), aw.x,
               fmaf(fmaxf((float)a1[1] + da.y, 0.f), aw.y,
               fmaf(fmaxf((float)a1[2] + da.z, 0.f), aw.z,
                    fmaxf((float)a1[3] + da.w, 0.f) * aw.w)));
#pragma unroll
    for (int off = 1; off < 32; off <<= 1) {
      p0 += __shfl_xor(p0, off);
      p1 += __shfl_xor(p1, off);
    }
    float t0 = 1.f / (1.f + expf(-(p0 + ab2)));
    float t1 = 1.f / (1.f + expf(-(p1 + ab2)));
    aA += t0 + t1;
    aH0 = fmaf(t0, h0[0], fmaf(t1, h1[0], aH0));
    aH1 = fmaf(t0, h0[1], fmaf(t1, h1[1], aH1));
    aH2 = fmaf(t0, h0[2], fmaf(t1, h1[2], aH2));
    aH3 = fmaf(t0, h0[3], fmaf(t1, h1[3], aH3));
  }
  if (i < e) {
    int s0 = sortedSrc[i];
    const _Float16* Z0 = Zsrc + (size_t)s0 * 256 + 4 * c;
    f16x4 m0 = *(const f16x4*)Z0, a0 = *(const f16x4*)(Z0 + 128);
    float h00 = fmaxf((float)m0[0] + dm.x, 0.f), h01 = fmaxf((float)m0[1] + dm.y, 0.f);
    float h02 = fmaxf((float)m0[2] + dm.z, 0.f), h03 = fmaxf((float)m0[3] + dm.w, 0.f);
    float p0 = fmaf(fmaxf((float)a0[0] + da.x, 0.f), aw.x,
               fmaf(fmaxf((float)a0[1] + da.y, 0.f), aw.y,
               fmaf(fmaxf((float)a0[2] + da.z, 0.f), aw.z,
                    fmaxf((float)a0[3] + da.w, 0.f) * aw.w)));
#pragma unroll
    for (int off = 1; off < 32; off <<= 1) p0 += __shfl_xor(p0, off);
    float t0 = 1.f / (1.f + expf(-(p0 + ab2)));
    aA += t0;
    aH0 = fmaf(t0, h00, aH0);
    aH1 = fmaf(t0, h01, aH1);
    aH2 = fmaf(t0, h02, aH2);
    aH3 = fmaf(t0, h03, aH3);
  }

  *(float4*)(aggH + (size_t)node * DD + 4 * c) = (float4){aH0, aH1, aH2, aH3};
  if (c == 0) aggA[node] = aA;
}

// ---------------- node update (W2 folded; optional fused Z-prep for next step) ----
// out = relu(h@U1top + aggH@W2U + aggA (x) v2 + upd_b1) @ U2 + upd_b2 + h + g
// DOZ: additionally compute Zsrc/Zdst = out @ Wbig for this block's 64 rows.
template <int DOZ>
__global__ __launch_bounds__(256, 2) void node_mfma_kernel(
    const float* __restrict__ h, const float* __restrict__ aggH,
    const float* __restrict__ aggA, const float* __restrict__ v2,
    const short* __restrict__ U1hiT, const short* __restrict__ U1loT,
    const short* __restrict__ U2hiT, const short* __restrict__ U2loT,
    const float* __restrict__ upd_b1, const float* __restrict__ upd_b2,
    const float* __restrict__ g, float* __restrict__ out, int N,
    const short* __restrict__ WbigF, const float* __restrict__ msg_b1,
    const float* __restrict__ att_b1, _Float16* __restrict__ Zsrc,
    float* __restrict__ Zdst) {
  __shared__ __align__(16) short smem[29184];
  short* WT1hi = smem;            // 128 cols x 40
  short* WT1lo = smem + 5120;
  short* HIDlo = smem + 10240;
  short* HIDhi = smem + 20480;

  const int tid = threadIdx.x;
  const int wave = tid >> 6;
  const int lane = tid & 63;
  const int m16 = lane & 15;
  const int q = lane >> 4;

  const int n0 = blockIdx.x * 64;
  const int nA = n0 + wave * 16 + m16;
  const int nAc = min(nA, N - 1);

  short8 a1h[8], a1l[8];
  {
    const float* rs = h + (size_t)nAc * DD;
    const float* rd = aggH + (size_t)nAc * DD;
#pragma unroll
    for (int t = 0; t < 8; ++t) {
      const float* base = ((t < 4) ? (rs + t * 32) : (rd + (t - 4) * 32)) + q * 8;
      float4 v0 = *(const float4*)(base);
      float4 v1 = *(const float4*)(base + 4);
      float f[8] = {v0.x, v0.y, v0.z, v0.w, v1.x, v1.y, v1.z, v1.w};
      short8 hh, ll;
#pragma unroll
      for (int j = 0; j < 8; ++j) { short hi, lo; split2(f[j], hi, lo); hh[j] = hi; ll[j] = lo; }
      a1h[t] = hh; a1l[t] = ll;
    }
  }

  f32x4 acc[8];
#pragma unroll
  for (int n = 0; n < 8; ++n) {
    float b = upd_b1[n * 16 + m16];
    acc[n] = (f32x4){b, b, b, b};
  }

  for (int t = 0; t < 8; ++t) {
    __syncthreads();
#pragma unroll
    for (int r = 0; r < 4; ++r) {
      int idx = tid + 256 * r;
      int comp = idx >> 9;
      int cid = idx & 511;
      int col = cid >> 2, sub = cid & 3;
      const short* gsrc = (comp ? U1loT : U1hiT) + col * 256 + t * 32 + sub * 8;
      short* ldst = (comp ? WT1lo : WT1hi) + col * 40 + sub * 8;
      *(short8*)ldst = *(const short8*)gsrc;
    }
    __syncthreads();
#pragma unroll
    for (int n = 0; n < 8; ++n) {
      const short* bp = WT1hi + (n * 16 + m16) * 40 + q * 8;
      short8 bh = *(const short8*)bp;
      short8 bl = *(const short8*)(bp + 5120);
      acc[n] = __builtin_amdgcn_mfma_f32_16x16x32_bf16(a1h[t], bh, acc[n], 0, 0, 0);
      acc[n] = __builtin_amdgcn_mfma_f32_16x16x32_bf16(a1l[t], bh, acc[n], 0, 0, 0);
      acc[n] = __builtin_amdgcn_mfma_f32_16x16x32_bf16(a1h[t], bl, acc[n], 0, 0, 0);
    }
  }

  // fold in aggA (x) v2
  {
    float aAv[4];
#pragma unroll
    for (int r = 0; r < 4; ++r) aAv[r] = aggA[min(n0 + wave * 16 + q * 4 + r, N - 1)];
#pragma unroll
    for (int n = 0; n < 8; ++n) {
      float vv = v2[n * 16 + m16];
#pragma unroll
      for (int r = 0; r < 4; ++r) acc[n][r] = fmaf(aAv[r], vv, acc[n][r]);
    }
  }

  __syncthreads();
#pragma unroll
  for (int n = 0; n < 8; ++n) {
    int col = n * 16 + m16;
#pragma unroll
    for (int r = 0; r < 4; ++r) {
      int row = wave * 16 + q * 4 + r;
      float v = fmaxf(acc[n][r], 0.f);
      short hi, lo; split2(v, hi, lo);
      HIDhi[row * 136 + col] = hi;
      HIDlo[row * 136 + col] = lo;
    }
  }
  __syncthreads();

  short8 a2h[4], a2l[4];
  {
    int mrow = wave * 16 + m16;
#pragma unroll
    for (int t = 0; t < 4; ++t) {
      a2h[t] = *(const short8*)(HIDhi + mrow * 136 + t * 32 + q * 8);
      a2l[t] = *(const short8*)(HIDlo + mrow * 136 + t * 32 + q * 8);
    }
  }

  f32x4 acc2[8];
#pragma unroll
  for (int n = 0; n < 8; ++n) {
    float b = upd_b2[n * 16 + m16];
    acc2[n] = (f32x4){b, b, b, b};
  }

  for (int t = 0; t < 4; ++t) {
    __syncthreads();
#pragma unroll
    for (int r = 0; r < 4; ++r) {
      int idx = tid + 256 * r;
      int comp = idx >> 9;
      int cid = idx & 511;
      int col = cid >> 2, sub = cid & 3;
      const short* gsrc = (comp ? U2loT : U2hiT) + col * 128 + t * 32 + sub * 8;
      short* ldst = (comp ? WT1lo : WT1hi) + col * 40 + sub * 8;
      *(short8*)ldst = *(const short8*)gsrc;
    }
    __syncthreads();
#pragma unroll
    for (int n = 0; n < 8; ++n) {
      const short* bp = WT1hi + (n * 16 + m16) * 40 + q * 8;
      short8 bh = *(const short8*)bp;
      short8 bl = *(const short8*)(bp + 5120);
      acc2[n] = __builtin_amdgcn_mfma_f32_16x16x32_bf16(a2h[t], bh, acc2[n], 0, 0, 0);
      acc2[n] = __builtin_amdgcn_mfma_f32_16x16x32_bf16(a2l[t], bh, acc2[n], 0, 0, 0);
      acc2[n] = __builtin_amdgcn_mfma_f32_16x16x32_bf16(a2h[t], bl, acc2[n], 0, 0, 0);
    }
  }

  // epilogue: out = acc2 + h + g  (also stage into LDS for fused Z-prep)
  float* OUTs = (float*)smem;  // 64 x 132 fp32 (overlays WT1/HID; 33792 B)
  if (DOZ) __syncthreads();    // all WT1 reads done before overlay
#pragma unroll
  for (int r = 0; r < 4; ++r) {
    int rowN = n0 + wave * 16 + q * 4 + r;
    int rc = min(rowN, N - 1);
#pragma unroll
    for (int n = 0; n < 8; ++n) {
      int col = n * 16 + m16;
      float v = acc2[n][r] + h[(size_t)rc * DD + col] + g[col];
      if (DOZ) OUTs[(wave * 16 + q * 4 + r) * 132 + col] = v;
      if (rowN < N) out[(size_t)rowN * DD + col] = v;
    }
  }

  if (DOZ) {
    __syncthreads();
    // Z-GEMM for this block's 64 rows: wave w -> cols [128w, 128w+128)
#pragma unroll
    for (int half = 0; half < 2; ++half) {
      f32x4 zacc[4][4];
#pragma unroll
      for (int nt = 0; nt < 4; ++nt) {
        int col = wave * 128 + half * 64 + nt * 16 + m16;
        float b = (col < 128) ? msg_b1[col] : ((col < 256) ? att_b1[col - 128] : 0.f);
#pragma unroll
        for (int mt = 0; mt < 4; ++mt) zacc[mt][nt] = (f32x4){b, b, b, b};
      }
      for (int c = 0; c < 4; ++c) {
        short8 ah[4], al[4];
#pragma unroll
        for (int mt = 0; mt < 4; ++mt) {
          const float* p = OUTs + (mt * 16 + m16) * 132 + c * 32 + q * 8;
          float4 v0 = *(const float4*)p;
          float4 v1 = *(const float4*)(p + 4);
          float f[8] = {v0.x, v0.y, v0.z, v0.w, v1.x, v1.y, v1.z, v1.w};
#pragma unroll
          for (int j = 0; j < 8; ++j) {
            short hi, lo; splitT(f[j], hi, lo); ah[mt][j] = hi; al[mt][j] = lo;
          }
        }
#pragma unroll
        for (int nt = 0; nt < 4; ++nt) {
          int ng = wave * 8 + half * 4 + nt;
          const short* bp = WbigF + ((size_t)((c * 32 + ng) * 2) * 64 + lane) * 8;
          short8 bh = *(const short8*)bp;
          short8 bl = *(const short8*)(bp + 512);
#pragma unroll
          for (int mt = 0; mt < 4; ++mt) {
            zacc[mt][nt] = __builtin_amdgcn_mfma_f32_16x16x32_bf16(ah[mt], bh, zacc[mt][nt], 0, 0, 0);
            zacc[mt][nt] = __builtin_amdgcn_mfma_f32_16x16x32_bf16(al[mt], bh, zacc[mt][nt], 0, 0, 0);
            zacc[mt][nt] = __builtin_amdgcn_mfma_f32_16x16x32_bf16(ah[mt], bl, zacc[mt][nt], 0, 0, 0);
          }
        }
      }
#pragma unroll
      for (int mt = 0; mt < 4; ++mt)
#pragma unroll
        for (int r = 0; r < 4; ++r) {
          int row = n0 + mt * 16 + q * 4 + r;
          if (row < N) {
#pragma unroll
            for (int nt = 0; nt < 4; ++nt) {
              int col = wave * 128 + half * 64 + nt * 16 + m16;
              float v = zacc[mt][nt][r];
              if (col < 256) Zsrc[(size_t)row * 256 + col] = (_Float16)v;
              else           Zdst[(size_t)row * 256 + (col - 256)] = v;
            }
          }
        }
    }
  }
}

extern "C" void kernel_launch(void* const* d_in, const int* in_sizes, int n_in,
                              void* d_out, int out_size, void* d_ws, size_t ws_size,
                              hipStream_t stream) {
  const float* x = (const float*)d_in[0];
  const int* ei = (const int*)d_in[1];
  const float* msg_W1 = (const float*)d_in[2];
  const float* msg_b1 = (const float*)d_in[3];
  const float* msg_W2 = (const float*)d_in[4];
  const float* msg_b2 = (const float*)d_in[5];
  const float* upd_W1 = (const float*)d_in[6];
  const float* upd_b1 = (const float*)d_in[7];
  const float* upd_W2 = (const float*)d_in[8];
  const float* upd_b2 = (const float*)d_in[9];
  const float* att_W1 = (const float*)d_in[10];
  const float* att_b1 = (const float*)d_in[11];
  const float* att_W2 = (const float*)d_in[12];
  const float* att_b2 = (const float*)d_in[13];
  const float* glb_W = (const float*)d_in[14];
  const float* glb_b = (const float*)d_in[15];

  const int N = in_sizes[0] / DD;
  const int E = in_sizes[1] / 2;
  const int* src = ei;
  const int* dst = ei + E;

  float* out = (float*)d_out;
  float* aggH = (float*)d_ws;                  // N*128 f32
  float* aggA = aggH + (size_t)N * DD;         // N
  float* colsum = aggA + N;                    // 128
  float* g = colsum + DD;                      // 128
  float* W2U = g + DD;                         // 16384 f32
  float* v2 = W2U + 16384;                     // 128 f32
  short* WbigF = (short*)(v2 + DD);            // 131072 shorts
  short* U1hiT = WbigF + 131072;               // 32768
  short* U1loT = U1hiT + 32768;                // 32768
  short* U2hiT = U1loT + 32768;                // 16384
  short* U2loT = U2hiT + 16384;                // 16384
  int* bsum = (int*)(U2loT + 16384);           // 64 ints
  int* rowptr = bsum + 64;                     // N+1 ints
  int* sortedSrc = rowptr + ((N + 1 + 3) & ~3);
  _Float16* Zsrc = (_Float16*)(sortedSrc + ((E + 3) & ~3));  // N*256 fp16
  float* Zdst = (float*)(Zsrc + (size_t)N * 256);            // N*256 fp32
  int* cursor = (int*)aggH;                    // overlay during sort phase only

  wprep_kernel<<<65, 256, 0, stream>>>(msg_W2, msg_b2, upd_W1, W2U, v2);
  conv_kernel<<<256, 256, 0, stream>>>(msg_W1, att_W1, upd_W1, upd_W2, W2U,
                                       WbigF, U1hiT, U1loT, U2hiT, U2loT);
  zero128_kernel<<<1, 128, 0, stream>>>(colsum);
  colsum_kernel<<<256, 256, 0, stream>>>(x, colsum, N);
  glb_kernel<<<1, 128, 0, stream>>>(colsum, glb_W, glb_b, g, 1.0f / (float)N);

  // CSR build (edges identical both steps -> sort once per launch)
  hipMemsetAsync(rowptr, 0, (size_t)(N + 1) * sizeof(int), stream);
  hist_kernel<<<1024, 256, 0, stream>>>(dst, rowptr, E);
  const int nscan = N + 1;
  const int nb = (nscan + 1023) / 1024;
  scan1_kernel<<<nb, 1024, 0, stream>>>(rowptr, bsum, nscan);
  scan2_kernel<<<1, 1024, 0, stream>>>(bsum, nb);
  if (nb > 1) scan3_kernel<<<nb - 1, 1024, 0, stream>>>(rowptr, bsum, nscan);
  hipMemcpyAsync(cursor, rowptr, (size_t)N * sizeof(int), hipMemcpyDeviceToDevice, stream);
  scatter_kernel<<<1024, 256, 0, stream>>>(src, dst, cursor, sortedSrc, E);

  const int zgrid = (N + 31) / 32;
  const int agrid = (N + 7) / 8;
  const int ngrid = (N + 63) / 64;

  // step 0
  zprep_kernel<<<zgrid, 256, 0, stream>>>(x, WbigF, msg_b1, att_b1, Zsrc, Zdst, N);
  aggcsr_kernel<<<agrid, 256, 0, stream>>>(Zsrc, Zdst, rowptr, sortedSrc, att_W2, att_b2,
                                           aggH, aggA, N);
  node_mfma_kernel<1><<<ngrid, 256, 0, stream>>>(x, aggH, aggA, v2,
                                                 U1hiT, U1loT, U2hiT, U2loT,
                                                 upd_b1, upd_b2, g, out, N,
                                                 WbigF, msg_b1, att_b1, Zsrc, Zdst);
  // step 1
  aggcsr_kernel<<<agrid, 256, 0, stream>>>(Zsrc, Zdst, rowptr, sortedSrc, att_W2, att_b2,
                                           aggH, aggA, N);
  node_mfma_kernel<0><<<ngrid, 256, 0, stream>>>(out, aggH, aggA, v2,
                                                 U1hiT, U1loT, U2hiT, U2loT,
                                                 upd_b1, upd_b2, g, out, N,
                                                 WbigF, msg_b1, att_b1, Zsrc, Zdst);
}